// Round 13
// baseline (448.373 us; speedup 1.0000x reference)
//
#include <hip/hip_runtime.h>
#include <hip/hip_bf16.h>
#include <cstdint>

typedef unsigned short u16;
typedef unsigned int u32;
typedef __attribute__((ext_vector_type(8))) short short8;   // 8 bf16 MFMA A/B frag
typedef __attribute__((ext_vector_type(4))) float f32x4;    // MFMA C/D frag
typedef __attribute__((ext_vector_type(4))) unsigned int u32x4;
typedef __attribute__((ext_vector_type(4))) unsigned short u16x4;

#define REV 15.91549431f   // 100/(2*pi): the "100*pos" angle in revolutions

// MEASUREMENT ROUND: each kernel internally repeats its (idempotent) body
// REP_x times so every kernel's duration clears the ~41us fillBuffer floor
// and surfaces in rocprof top-5. Per-iteration cost = dur / REP_x.
#define REP_PREP 3
#define REP_PROJ 16
#define REP_ATTN 8
#define REP_OUTG 16

// ---------- helpers ----------
__device__ __forceinline__ u16 f2b(float x) { return __builtin_bit_cast(u16, (__bf16)x); }
__device__ __forceinline__ u16 f2h(float x) { return __builtin_bit_cast(u16, (_Float16)x); }
__device__ __forceinline__ float c_dim_f(int f) {
    const float c[8] = {1.0f, 0.42169650f, 0.17782794f, 0.074989421f,
                        0.031622777f, 0.013335214f, 0.0056234132f, 0.0023713737f};
    return c[f];
}
__device__ __forceinline__ void gload_lds16(const void* g, void* l) {
    __builtin_amdgcn_global_load_lds((const __attribute__((address_space(1))) u32*)g,
                                     (__attribute__((address_space(3))) u32*)l, 16, 0, 0);
}

// ---------- prep: f32->bf16 cvt (z 0..6) + geometry weights (z 7..10) ----------
__global__ __launch_bounds__(256) void prep_k(const float* __restrict__ s0,
                                              const float* __restrict__ s1,
                                              const float* __restrict__ s2,
                                              const float* __restrict__ s3,
                                              const float* __restrict__ s4,
                                              const float* __restrict__ s5,
                                              const float* __restrict__ s6,
                                              const float* __restrict__ box,
                                              const float* __restrict__ WG,
                                              const float* __restrict__ bG,
                                              u16* __restrict__ dstX,
                                              u16* __restrict__ dstW,
                                              u16* __restrict__ outW) {
    __shared__ char embs[256 * 128];   // [256 pairs][64 bf16] rows, 128B each
    const int z = blockIdx.z;
    const int t = threadIdx.x;

    for (int rep = 0; rep < REP_PREP; ++rep) {
        if (z < 7) {
            if (z < 3 || blockIdx.x < 256) {
                const float* s;
                u16* dst;
                if (z < 3) {
                    s = (z == 0) ? s0 : (z == 1) ? s1 : s2;
                    dst = dstX + (size_t)z * 1048576;
                } else {
                    s = (z == 3) ? s3 : (z == 4) ? s4 : (z == 5) ? s5 : s6;
                    dst = dstW + (size_t)(z - 3) * 262144;
                }
                int i = (blockIdx.x * 256 + t) * 4;
                float4 v = *(const float4*)&s[i];
                u16x4 o = { f2b(v.x), f2b(v.y), f2b(v.z), f2b(v.w) };
                *(u16x4*)&dst[i] = o;
            }
            continue;
        }

        // ---------------- geometry ----------------
        const int wave = t >> 6, lane = t & 63;
        const int b = z - 7;
        const int jt = blockIdx.x & 1, ii = blockIdx.x >> 1;
        const int j = (jt << 8) + t;
        const int swz = (t & 7) << 4;

        float4 bi = *(const float4*)&box[(size_t)(((b << 9) + ii) << 2)];
        float4 bj = *(const float4*)&box[(size_t)(((b << 9) + j) << 2)];
        float cxi = (bi.x + bi.z) * 0.5f, cyi = (bi.y + bi.w) * 0.5f;
        float wdi = bi.z - bi.x + 1.0f,   hgi = bi.w - bi.y + 1.0f;
        float cxj = (bj.x + bj.z) * 0.5f, cyj = (bj.y + bj.w) * 0.5f;
        float wdj = bj.z - bj.x + 1.0f,   hgj = bj.w - bj.y + 1.0f;

        float pos[4];
        pos[0] = __logf(fmaxf(fabsf((cxi - cxj) / wdi), 1e-3f));
        pos[1] = __logf(fmaxf(fabsf((cyi - cyj) / hgi), 1e-3f));
        pos[2] = __logf(wdi) - __logf(wdj);
        pos[3] = __logf(hgi) - __logf(hgj);

#pragma unroll
        for (int p = 0; p < 4; p++) {
            float rev = pos[p] * REV;
            u32x4 sp, cp;
#pragma unroll
            for (int f = 0; f < 4; f++) {
                float a0 = rev * c_dim_f(2 * f), a1 = rev * c_dim_f(2 * f + 1);
                sp[f] = (u32)f2b(__builtin_amdgcn_sinf(a0)) | ((u32)f2b(__builtin_amdgcn_sinf(a1)) << 16);
                cp[f] = (u32)f2b(__builtin_amdgcn_cosf(a0)) | ((u32)f2b(__builtin_amdgcn_cosf(a1)) << 16);
            }
            *(u32x4*)(embs + (((t << 7) + (p << 4)) ^ swz)) = sp;
            *(u32x4*)(embs + (((t << 7) + 64 + (p << 4)) ^ swz)) = cp;
        }

        const int hh = lane & 15;
        const int ko = (lane >> 4) << 3;
        short8 bf0 = {0,0,0,0,0,0,0,0}, bf1 = {0,0,0,0,0,0,0,0};
        float bGh = 0.0f;
        if (hh < 8) {
            const float* wrow = WG + hh * 64;
#pragma unroll
            for (int e = 0; e < 8; e++) {
                bf0[e] = (short)f2b(wrow[ko + e]);
                bf1[e] = (short)f2b(wrow[32 + ko + e]);
            }
            bGh = bG[hh];
        }
        __syncthreads();

#pragma unroll
        for (int tt = 0; tt < 4; tt++) {
            int mt = (wave << 2) + tt;
            int row = (mt << 4) + hh;
            int rswz = (row & 7) << 4;
            short8 a0v = *(const short8*)(embs + (((row << 7) + (ko << 1)) ^ rswz));
            short8 a1v = *(const short8*)(embs + (((row << 7) + 64 + (ko << 1)) ^ rswz));
            f32x4 acc = {0.f, 0.f, 0.f, 0.f};
            acc = __builtin_amdgcn_mfma_f32_16x16x32_bf16(a0v, bf0, acc, 0, 0, 0);
            acc = __builtin_amdgcn_mfma_f32_16x16x32_bf16(a1v, bf1, acc, 0, 0, 0);
            if (hh < 8) {
                int j0 = (jt << 8) + (mt << 4) + ((lane >> 4) << 2);
                u16x4 ow;
#pragma unroll
                for (int r = 0; r < 4; r++)
                    ow[r] = f2h(fmaxf(acc[r] + bGh, 1e-6f) * 1024.0f);
                *(u16x4*)&outW[((size_t)((b << 3) + hh) << 18) + ((size_t)ii << 9) + j0] = ow;
            }
        }
        __syncthreads();   // next rep rewrites embs
    }
}

// ---------- fused flash attention: p = w * e^(0.125*QK^T - m), O = PV/l ----------
__global__ __launch_bounds__(256) void attn_k(const u16* __restrict__ Qb,
                                              const u16* __restrict__ Kb,
                                              const u16* __restrict__ VT,
                                              const u16* __restrict__ Wp,
                                              u16* __restrict__ ATT) {
    __shared__ u16 Pl[4][16 * 68];
    __shared__ float Mrg[3][64][25];
    const int t = threadIdx.x;
    const int wave = t >> 6, lane = t & 63;
    const int c = lane & 15, g = lane >> 4;
    const int bid = blockIdx.x;
    const int qb = bid & 31, bh = bid >> 5;
    const int b = bh >> 3, h = bh & 7;
    const int q0 = qb << 4;

    const u16* Qp = Qb + ((size_t)bh << 15);
    const u16* Kp = Kb + ((size_t)bh << 15);
    const u16* Vp = VT + ((size_t)bh << 15);
    const _Float16* Bp = (const _Float16*)Wp + ((size_t)bh << 18) + ((size_t)q0 << 9);

    for (int rep = 0; rep < REP_ATTN; ++rep) {
        short8 qf[2];
#pragma unroll
        for (int ks = 0; ks < 2; ks++)
            qf[ks] = *(const short8*)&Qp[(size_t)(q0 + c) * 64 + ks * 32 + g * 8];

        f32x4 o[4] = {};
        float m[4] = {-1e30f, -1e30f, -1e30f, -1e30f};
        float l[4] = {0.f, 0.f, 0.f, 0.f};

        for (int kt = 0; kt < 2; kt++) {
            const int k0 = ((wave << 1) + kt) << 6;
            short8 kf[4][2], vf[4][2];
#pragma unroll
            for (int jj = 0; jj < 4; jj++)
#pragma unroll
                for (int ks = 0; ks < 2; ks++) {
                    kf[jj][ks] = *(const short8*)&Kp[(size_t)(k0 + jj * 16 + c) * 64 + ks * 32 + g * 8];
                    vf[jj][ks] = *(const short8*)&Vp[(size_t)(jj * 16 + c) * 512 + k0 + ks * 32 + g * 8];
                }
            float wgt[4][4];
#pragma unroll
            for (int jj = 0; jj < 4; jj++)
#pragma unroll
                for (int r = 0; r < 4; r++)
                    wgt[jj][r] = (float)Bp[(size_t)(g * 4 + r) * 512 + k0 + jj * 16 + c];

            f32x4 sa[4] = {};
            __builtin_amdgcn_s_setprio(1);
#pragma unroll
            for (int jj = 0; jj < 4; jj++)
#pragma unroll
                for (int ks = 0; ks < 2; ks++)
                    sa[jj] = __builtin_amdgcn_mfma_f32_16x16x32_bf16(qf[ks], kf[jj][ks], sa[jj], 0, 0, 0);
            __builtin_amdgcn_s_setprio(0);

            float s[4][4];
#pragma unroll
            for (int r = 0; r < 4; r++) {
#pragma unroll
                for (int jj = 0; jj < 4; jj++)
                    s[jj][r] = sa[jj][r] * 0.125f;
                float v = fmaxf(fmaxf(s[0][r], s[1][r]), fmaxf(s[2][r], s[3][r]));
#pragma unroll
                for (int off = 1; off < 16; off <<= 1)
                    v = fmaxf(v, __shfl_xor(v, off));
                float mn = fmaxf(m[r], v);
                float alpha = __expf(m[r] - mn);
                m[r] = mn;
                float rs = 0.f;
#pragma unroll
                for (int jj = 0; jj < 4; jj++) {
                    float p = wgt[jj][r] * __expf(s[jj][r] - mn);
                    s[jj][r] = p;
                    rs += p;
                }
#pragma unroll
                for (int off = 1; off < 16; off <<= 1)
                    rs += __shfl_xor(rs, off);
                l[r] = l[r] * alpha + rs;
#pragma unroll
                for (int jjo = 0; jjo < 4; jjo++)
                    o[jjo][r] *= alpha;
            }

#pragma unroll
            for (int jj = 0; jj < 4; jj++)
#pragma unroll
                for (int r = 0; r < 4; r++)
                    Pl[wave][(g * 4 + r) * 68 + jj * 16 + c] = f2b(s[jj][r]);
            asm volatile("s_waitcnt lgkmcnt(0)" ::: "memory");
            __builtin_amdgcn_sched_barrier(0);

            short8 pa[2];
#pragma unroll
            for (int ks = 0; ks < 2; ks++)
                pa[ks] = *(const short8*)&Pl[wave][c * 68 + ks * 32 + g * 8];
            __builtin_amdgcn_s_setprio(1);
#pragma unroll
            for (int jjo = 0; jjo < 4; jjo++)
#pragma unroll
                for (int ks = 0; ks < 2; ks++)
                    o[jjo] = __builtin_amdgcn_mfma_f32_16x16x32_bf16(pa[ks], vf[jjo][ks], o[jjo], 0, 0, 0);
            __builtin_amdgcn_s_setprio(0);
            __builtin_amdgcn_sched_barrier(0);
        }

        if (wave > 0) {
#pragma unroll
            for (int r = 0; r < 4; r++) {
                Mrg[wave - 1][lane][r] = m[r];
                Mrg[wave - 1][lane][4 + r] = l[r];
#pragma unroll
                for (int jjo = 0; jjo < 4; jjo++)
                    Mrg[wave - 1][lane][8 + jjo * 4 + r] = o[jjo][r];
            }
        }
        __syncthreads();
        if (wave == 0) {
#pragma unroll
            for (int w = 0; w < 3; w++) {
#pragma unroll
                for (int r = 0; r < 4; r++) {
                    float m1 = Mrg[w][lane][r];
                    float l1 = Mrg[w][lane][4 + r];
                    float mn = fmaxf(m[r], m1);
                    float a0 = __expf(m[r] - mn), a1 = __expf(m1 - mn);
                    m[r] = mn;
                    l[r] = l[r] * a0 + l1 * a1;
#pragma unroll
                    for (int jjo = 0; jjo < 4; jjo++)
                        o[jjo][r] = o[jjo][r] * a0 + Mrg[w][lane][8 + jjo * 4 + r] * a1;
                }
            }
#pragma unroll
            for (int r = 0; r < 4; r++) {
                float inv = 1.0f / l[r];
                int row = q0 + g * 4 + r;
#pragma unroll
                for (int jjo = 0; jjo < 4; jjo++)
                    ATT[(size_t)(((b << 9) + row) << 9) + (h << 6) + jjo * 16 + c] = f2b(o[jjo][r] * inv);
            }
        }
        __syncthreads();   // Mrg reuse across reps
    }
}

// ---------- merged projection GEMM (dbuf counted-vmcnt staging) ----------
__global__ __launch_bounds__(256) void proj_k(const u16* __restrict__ Xall,
                                              const u16* __restrict__ Wall,
                                              const float* __restrict__ bq,
                                              const float* __restrict__ bk,
                                              const float* __restrict__ bv,
                                              u16* __restrict__ Qb,
                                              u16* __restrict__ Kb,
                                              u16* __restrict__ VT) {
    __shared__ u16 As[2][64 * 32];
    __shared__ u16 Bs[2][64 * 32];

    const int t = threadIdx.x;
    const int wave = t >> 6, lane = t & 63;
    const int wr = wave >> 1, wc = wave & 1;
    const int m0 = blockIdx.y * 64, n0 = blockIdx.x * 64;
    const int z = blockIdx.z;

    const u16* A  = Xall + (size_t)z * 1048576;
    const u16* Bm = Wall + (size_t)z * 262144;
    const float* bias = (z == 0) ? bq : (z == 1) ? bk : bv;
    u16* out = (z == 0) ? Qb : (z == 1) ? Kb : VT;

    const int srow = t >> 2;
    const int scol = (((t & 3) ^ ((t >> 3) & 3)) << 3);
    const int c = lane & 15, g = lane >> 4;
    const int gsw = (g ^ ((c >> 1) & 3)) << 3;

    const size_t arow = (size_t)(m0 + srow) * 512 + scol;
    const size_t brow = (size_t)(n0 + srow) * 512 + scol;

    for (int rep = 0; rep < REP_PROJ; ++rep) {
        f32x4 acc[2][2] = {};
        gload_lds16(&A[arow], &As[0][t * 8]);
        gload_lds16(&Bm[brow], &Bs[0][t * 8]);

        int cur = 0;
        for (int k0 = 0; k0 < 512; k0 += 32, cur ^= 1) {
            if (k0 + 32 < 512) {
                gload_lds16(&A[arow + k0 + 32], &As[cur ^ 1][t * 8]);
                gload_lds16(&Bm[brow + k0 + 32], &Bs[cur ^ 1][t * 8]);
                asm volatile("s_waitcnt vmcnt(2)" ::: "memory");
            } else {
                asm volatile("s_waitcnt vmcnt(0)" ::: "memory");
            }
            __builtin_amdgcn_s_barrier();
            __builtin_amdgcn_sched_barrier(0);
            short8 af[2], bfr[2];
#pragma unroll
            for (int i = 0; i < 2; i++)
                af[i] = *(const short8*)&As[cur][(wr * 32 + i * 16 + c) * 32 + gsw];
#pragma unroll
            for (int jj = 0; jj < 2; jj++)
                bfr[jj] = *(const short8*)&Bs[cur][(wc * 32 + jj * 16 + c) * 32 + gsw];
#pragma unroll
            for (int i = 0; i < 2; i++)
#pragma unroll
                for (int jj = 0; jj < 2; jj++)
                    acc[i][jj] = __builtin_amdgcn_mfma_f32_16x16x32_bf16(af[i], bfr[jj], acc[i][jj], 0, 0, 0);
            __builtin_amdgcn_sched_barrier(0);
            __builtin_amdgcn_s_barrier();
        }

#pragma unroll
        for (int i = 0; i < 2; i++)
#pragma unroll
            for (int jj = 0; jj < 2; jj++)
#pragma unroll
                for (int r = 0; r < 4; r++) {
                    int row = m0 + wr * 32 + i * 16 + ((lane >> 4) << 2) + r;
                    int col = n0 + wc * 32 + jj * 16 + (lane & 15);
                    float v = acc[i][jj][r] + bias[col];
                    int b = row >> 9, rr = row & 511, h = col >> 6, d = col & 63;
                    if (z < 2)
                        out[(size_t)((((b << 3) + h) << 9) + rr) * 64 + d] = f2b(v);
                    else
                        out[(size_t)((((b << 3) + h) << 6) + d) * 512 + rr] = f2b(v);
                }
    }
}

// ---------- output GEMM (dbuf staging) ----------
__global__ __launch_bounds__(256) void outg_k(const u16* __restrict__ A,
                                              const u16* __restrict__ Bm,
                                              const float* __restrict__ bias,
                                              float* __restrict__ outF) {
    __shared__ u16 As[2][64 * 32];
    __shared__ u16 Bs[2][64 * 32];

    const int t = threadIdx.x;
    const int wave = t >> 6, lane = t & 63;
    const int wr = wave >> 1, wc = wave & 1;
    const int m0 = blockIdx.y * 64, n0 = blockIdx.x * 64;

    const int srow = t >> 2;
    const int scol = (((t & 3) ^ ((t >> 3) & 3)) << 3);
    const int c = lane & 15, g = lane >> 4;
    const int gsw = (g ^ ((c >> 1) & 3)) << 3;

    const size_t arow = (size_t)(m0 + srow) * 512 + scol;
    const size_t brow = (size_t)(n0 + srow) * 512 + scol;

    for (int rep = 0; rep < REP_OUTG; ++rep) {
        f32x4 acc[2][2] = {};
        gload_lds16(&A[arow], &As[0][t * 8]);
        gload_lds16(&Bm[brow], &Bs[0][t * 8]);

        int cur = 0;
        for (int k0 = 0; k0 < 512; k0 += 32, cur ^= 1) {
            if (k0 + 32 < 512) {
                gload_lds16(&A[arow + k0 + 32], &As[cur ^ 1][t * 8]);
                gload_lds16(&Bm[brow + k0 + 32], &Bs[cur ^ 1][t * 8]);
                asm volatile("s_waitcnt vmcnt(2)" ::: "memory");
            } else {
                asm volatile("s_waitcnt vmcnt(0)" ::: "memory");
            }
            __builtin_amdgcn_s_barrier();
            __builtin_amdgcn_sched_barrier(0);
            short8 af[2], bfr[2];
#pragma unroll
            for (int i = 0; i < 2; i++)
                af[i] = *(const short8*)&As[cur][(wr * 32 + i * 16 + c) * 32 + gsw];
#pragma unroll
            for (int jj = 0; jj < 2; jj++)
                bfr[jj] = *(const short8*)&Bs[cur][(wc * 32 + jj * 16 + c) * 32 + gsw];
#pragma unroll
            for (int i = 0; i < 2; i++)
#pragma unroll
                for (int jj = 0; jj < 2; jj++)
                    acc[i][jj] = __builtin_amdgcn_mfma_f32_16x16x32_bf16(af[i], bfr[jj], acc[i][jj], 0, 0, 0);
            __builtin_amdgcn_sched_barrier(0);
            __builtin_amdgcn_s_barrier();
        }

#pragma unroll
        for (int i = 0; i < 2; i++)
#pragma unroll
            for (int jj = 0; jj < 2; jj++)
#pragma unroll
                for (int r = 0; r < 4; r++) {
                    int row = m0 + wr * 32 + i * 16 + ((lane >> 4) << 2) + r;
                    int col = n0 + wc * 32 + jj * 16 + (lane & 15);
                    outF[((size_t)row << 9) + col] = acc[i][jj][r] + bias[col];
                }
    }
}

// ---------- launch ----------
extern "C" void kernel_launch(void* const* d_in, const int* in_sizes, int n_in,
                              void* d_out, int out_size, void* d_ws, size_t ws_size,
                              hipStream_t stream) {
    const float* inq = (const float*)d_in[0];
    const float* ink = (const float*)d_in[1];
    const float* inv = (const float*)d_in[2];
    const float* box = (const float*)d_in[3];
    const float* Wq  = (const float*)d_in[4];
    const float* bq  = (const float*)d_in[5];
    const float* Wk  = (const float*)d_in[6];
    const float* bk  = (const float*)d_in[7];
    const float* Wv  = (const float*)d_in[8];
    const float* bv  = (const float*)d_in[9];
    const float* Wo  = (const float*)d_in[10];
    const float* bo  = (const float*)d_in[11];
    const float* WG  = (const float*)d_in[12];
    const float* bG  = (const float*)d_in[13];

    u16* base = (u16*)d_ws;
    u16* Xall = base;                    // XQ,XK,XV bf16 (3 x 1,048,576)
    u16* Wall = base + 3145728;          // WQb,WKb,WVb,WOb bf16 (4 x 262,144)
    u16* Qb   = base + 4194304;          // [B,H,N,64] bf16
    u16* Kb   = base + 5242880;          // [B,H,N,64] bf16
    u16* VT   = base + 6291456;          // [B,H,64,N] bf16
    u16* ATT  = base + 7340032;          // [B,N,512] bf16
    u16* Wp   = base + 8388608;          // [B,H,N,N] f16 geometry weights

    prep_k<<<dim3(1024, 1, 11), 256, 0, stream>>>(inq, ink, inv, Wq, Wk, Wv, Wo,
                                                  box, WG, bG, Xall, Wall, Wp);

    proj_k<<<dim3(8, 32, 3), 256, 0, stream>>>(Xall, Wall, bq, bk, bv, Qb, Kb, VT);

    attn_k<<<dim3(1024), 256, 0, stream>>>(Qb, Kb, VT, Wp, ATT);

    outg_k<<<dim3(8, 32, 1), 256, 0, stream>>>(ATT, Wall + 786432, bo, (float*)d_out);
}

// Round 14
// 73.623 us; speedup vs baseline: 6.0902x; 6.0902x over previous
//
#include <hip/hip_runtime.h>
#include <hip/hip_bf16.h>
#include <cstdint>

typedef unsigned short u16;
typedef unsigned int u32;
typedef __attribute__((ext_vector_type(8))) short short8;   // 8 bf16 MFMA A/B frag
typedef __attribute__((ext_vector_type(4))) float f32x4;    // MFMA C/D frag
typedef __attribute__((ext_vector_type(4))) unsigned int u32x4;
typedef __attribute__((ext_vector_type(4))) unsigned short u16x4;

#define REV 15.91549431f   // 100/(2*pi): the "100*pos" angle in revolutions

// ---------- helpers ----------
__device__ __forceinline__ u16 f2b(float x) { return __builtin_bit_cast(u16, (__bf16)x); }
__device__ __forceinline__ u16 f2h(float x) { return __builtin_bit_cast(u16, (_Float16)x); }
__device__ __forceinline__ float c_dim_f(int f) {
    const float c[8] = {1.0f, 0.42169650f, 0.17782794f, 0.074989421f,
                        0.031622777f, 0.013335214f, 0.0056234132f, 0.0023713737f};
    return c[f];
}
__device__ __forceinline__ void gload_lds16(const void* g, void* l) {
    __builtin_amdgcn_global_load_lds((const __attribute__((address_space(1))) u32*)g,
                                     (__attribute__((address_space(3))) u32*)l, 16, 0, 0);
}

// ---------- prep: f32->bf16 cvt (z 0..6) + geometry weights (z 7..10) ----------
__global__ __launch_bounds__(256) void prep_k(const float* __restrict__ s0,
                                              const float* __restrict__ s1,
                                              const float* __restrict__ s2,
                                              const float* __restrict__ s3,
                                              const float* __restrict__ s4,
                                              const float* __restrict__ s5,
                                              const float* __restrict__ s6,
                                              const float* __restrict__ box,
                                              const float* __restrict__ WG,
                                              const float* __restrict__ bG,
                                              u16* __restrict__ dstX,
                                              u16* __restrict__ dstW,
                                              u16* __restrict__ outW) {
    __shared__ char embs[256 * 128];   // [256 pairs][64 bf16] rows, 128B each
    const int z = blockIdx.z;
    const int t = threadIdx.x;

    if (z < 7) {
        const float* s;
        u16* dst;
        if (z < 3) {
            s = (z == 0) ? s0 : (z == 1) ? s1 : s2;
            dst = dstX + (size_t)z * 1048576;
        } else {
            if (blockIdx.x >= 256) return;
            s = (z == 3) ? s3 : (z == 4) ? s4 : (z == 5) ? s5 : s6;
            dst = dstW + (size_t)(z - 3) * 262144;
        }
        int i = (blockIdx.x * 256 + t) * 4;
        float4 v = *(const float4*)&s[i];
        u16x4 o = { f2b(v.x), f2b(v.y), f2b(v.z), f2b(v.w) };
        *(u16x4*)&dst[i] = o;
        return;
    }

    // ---------------- geometry ----------------
    const int wave = t >> 6, lane = t & 63;
    const int b = z - 7;
    const int jt = blockIdx.x & 1, ii = blockIdx.x >> 1;
    const int j = (jt << 8) + t;
    const int swz = (t & 7) << 4;

    float4 bi = *(const float4*)&box[(size_t)(((b << 9) + ii) << 2)];
    float4 bj = *(const float4*)&box[(size_t)(((b << 9) + j) << 2)];
    float cxi = (bi.x + bi.z) * 0.5f, cyi = (bi.y + bi.w) * 0.5f;
    float wdi = bi.z - bi.x + 1.0f,   hgi = bi.w - bi.y + 1.0f;
    float cxj = (bj.x + bj.z) * 0.5f, cyj = (bj.y + bj.w) * 0.5f;
    float wdj = bj.z - bj.x + 1.0f,   hgj = bj.w - bj.y + 1.0f;

    float pos[4];
    pos[0] = __logf(fmaxf(fabsf((cxi - cxj) / wdi), 1e-3f));
    pos[1] = __logf(fmaxf(fabsf((cyi - cyj) / hgi), 1e-3f));
    pos[2] = __logf(wdi) - __logf(wdj);
    pos[3] = __logf(hgi) - __logf(hgj);

#pragma unroll
    for (int p = 0; p < 4; p++) {
        float rev = pos[p] * REV;
        u32x4 sp, cp;
#pragma unroll
        for (int f = 0; f < 4; f++) {
            float a0 = rev * c_dim_f(2 * f), a1 = rev * c_dim_f(2 * f + 1);
            sp[f] = (u32)f2b(__builtin_amdgcn_sinf(a0)) | ((u32)f2b(__builtin_amdgcn_sinf(a1)) << 16);
            cp[f] = (u32)f2b(__builtin_amdgcn_cosf(a0)) | ((u32)f2b(__builtin_amdgcn_cosf(a1)) << 16);
        }
        *(u32x4*)(embs + (((t << 7) + (p << 4)) ^ swz)) = sp;
        *(u32x4*)(embs + (((t << 7) + 64 + (p << 4)) ^ swz)) = cp;
    }

    const int hh = lane & 15;
    const int ko = (lane >> 4) << 3;
    short8 bf0 = {0,0,0,0,0,0,0,0}, bf1 = {0,0,0,0,0,0,0,0};
    float bGh = 0.0f;
    if (hh < 8) {
        const float* wrow = WG + hh * 64;
#pragma unroll
        for (int e = 0; e < 8; e++) {
            bf0[e] = (short)f2b(wrow[ko + e]);
            bf1[e] = (short)f2b(wrow[32 + ko + e]);
        }
        bGh = bG[hh];
    }
    __syncthreads();

#pragma unroll
    for (int tt = 0; tt < 4; tt++) {
        int mt = (wave << 2) + tt;
        int row = (mt << 4) + hh;
        int rswz = (row & 7) << 4;
        short8 a0v = *(const short8*)(embs + (((row << 7) + (ko << 1)) ^ rswz));
        short8 a1v = *(const short8*)(embs + (((row << 7) + 64 + (ko << 1)) ^ rswz));
        f32x4 acc = {0.f, 0.f, 0.f, 0.f};
        acc = __builtin_amdgcn_mfma_f32_16x16x32_bf16(a0v, bf0, acc, 0, 0, 0);
        acc = __builtin_amdgcn_mfma_f32_16x16x32_bf16(a1v, bf1, acc, 0, 0, 0);
        if (hh < 8) {
            int j0 = (jt << 8) + (mt << 4) + ((lane >> 4) << 2);
            u16x4 ow;
#pragma unroll
            for (int r = 0; r < 4; r++)
                ow[r] = f2h(fmaxf(acc[r] + bGh, 1e-6f) * 1024.0f);
            *(u16x4*)&outW[((size_t)((b << 3) + hh) << 18) + ((size_t)ii << 9) + j0] = ow;
        }
    }
}

// ---------- fused flash attention v2 ----------
// p = w * e^(0.125*QK^T - m), O = PV/l. 4 waves k-split. Changes vs v1:
//  * bias tile [16][512] f16 staged via 4 coalesced gload_lds16/thread,
//    g-XOR col swizzle (rule #21: inverse-swizzled global src + swizzled read)
//    -> LDS reads 2-way conflict-free, replaces 32 scattered 2B global loads.
//  * softmax reductions ILP-interleaved across the 4 r-rows (same tree,
//    bit-identical; ~4x less exposed shfl latency).
//  * no hand fences (plain LDS deps are compiler-tracked); Pl double-buffered
//    by kt so the compiler can overlap kt=1 loads with kt=0 compute.
__global__ __launch_bounds__(256, 3) void attn_k(const u16* __restrict__ Qb,
                                                 const u16* __restrict__ Kb,
                                                 const u16* __restrict__ VT,
                                                 const u16* __restrict__ Wp,
                                                 u16* __restrict__ ATT) {
    __shared__ _Float16 Wl[16 * 512];        // bias tile, swizzled (16KB)
    __shared__ u16 Pl[4][2][16 * 68];        // per-wave, per-kt P transpose (17.4KB)
    __shared__ float Mrg[3][64][25];         // merge partials (19.2KB)
    const int t = threadIdx.x;
    const int wave = t >> 6, lane = t & 63;
    const int c = lane & 15, g = lane >> 4;
    const int bid = blockIdx.x;
    const int qb = bid & 31, bh = bid >> 5;
    const int b = bh >> 3, h = bh & 7;
    const int q0 = qb << 4;

    const u16* Qp = Qb + ((size_t)bh << 15);
    const u16* Kp = Kb + ((size_t)bh << 15);
    const u16* Vp = VT + ((size_t)bh << 15);
    const char* Bg = (const char*)(Wp + ((size_t)bh << 18) + ((size_t)q0 << 9)); // 16KB contiguous

    // stage bias tile: dst chunk k of row rr <- src chunk k ^ (((rr>>2)&3)<<1)
#pragma unroll
    for (int p = 0; p < 4; p++) {
        int dstb = t * 16 + p * 4096;
        int rr = dstb >> 10;
        int chunk = (dstb & 1023) >> 4;
        int schunk = chunk ^ (((rr >> 2) & 3) << 1);
        gload_lds16(Bg + rr * 1024 + schunk * 16, (char*)Wl + dstb);
    }

    short8 qf[2];
#pragma unroll
    for (int ks = 0; ks < 2; ks++)
        qf[ks] = *(const short8*)&Qp[(size_t)(q0 + c) * 64 + ks * 32 + g * 8];

    f32x4 o[4] = {};
    float m[4] = {-1e30f, -1e30f, -1e30f, -1e30f};
    float l[4] = {0.f, 0.f, 0.f, 0.f};

    __syncthreads();   // bias tile staged (barrier drains vmcnt)

#pragma unroll
    for (int kt = 0; kt < 2; kt++) {
        const int k0 = ((wave << 1) + kt) << 6;
        short8 kf[4][2], vf[4][2];
#pragma unroll
        for (int jj = 0; jj < 4; jj++)
#pragma unroll
            for (int ks = 0; ks < 2; ks++) {
                kf[jj][ks] = *(const short8*)&Kp[(size_t)(k0 + jj * 16 + c) * 64 + ks * 32 + g * 8];
                vf[jj][ks] = *(const short8*)&Vp[(size_t)(jj * 16 + c) * 512 + k0 + ks * 32 + g * 8];
            }
        float wgt[4][4];
#pragma unroll
        for (int jj = 0; jj < 4; jj++)
#pragma unroll
            for (int r = 0; r < 4; r++)
                wgt[jj][r] = (float)Wl[(g * 4 + r) * 512 + ((k0 + jj * 16 + c) ^ (g << 4))];

        f32x4 sa[4] = {};
        __builtin_amdgcn_s_setprio(1);
#pragma unroll
        for (int jj = 0; jj < 4; jj++)
#pragma unroll
            for (int ks = 0; ks < 2; ks++)
                sa[jj] = __builtin_amdgcn_mfma_f32_16x16x32_bf16(qf[ks], kf[jj][ks], sa[jj], 0, 0, 0);
        __builtin_amdgcn_s_setprio(0);

        float s[4][4];
#pragma unroll
        for (int r = 0; r < 4; r++)
#pragma unroll
            for (int jj = 0; jj < 4; jj++)
                s[jj][r] = sa[jj][r] * 0.125f;

        // ---- ILP row-max over 64 k (4 independent shfl chains) ----
        float vmax[4];
#pragma unroll
        for (int r = 0; r < 4; r++)
            vmax[r] = fmaxf(fmaxf(s[0][r], s[1][r]), fmaxf(s[2][r], s[3][r]));
#pragma unroll
        for (int off = 1; off < 16; off <<= 1)
#pragma unroll
            for (int r = 0; r < 4; r++)
                vmax[r] = fmaxf(vmax[r], __shfl_xor(vmax[r], off));

        float alpha[4];
#pragma unroll
        for (int r = 0; r < 4; r++) {
            float mn = fmaxf(m[r], vmax[r]);
            alpha[r] = __expf(m[r] - mn);
            m[r] = mn;
        }

        float rs[4] = {0.f, 0.f, 0.f, 0.f};
#pragma unroll
        for (int r = 0; r < 4; r++)
#pragma unroll
            for (int jj = 0; jj < 4; jj++) {
                float p = wgt[jj][r] * __expf(s[jj][r] - m[r]);
                s[jj][r] = p;
                rs[r] += p;
            }
#pragma unroll
        for (int off = 1; off < 16; off <<= 1)
#pragma unroll
            for (int r = 0; r < 4; r++)
                rs[r] += __shfl_xor(rs[r], off);
#pragma unroll
        for (int r = 0; r < 4; r++)
            l[r] = l[r] * alpha[r] + rs[r];
#pragma unroll
        for (int jjo = 0; jjo < 4; jjo++)
#pragma unroll
            for (int r = 0; r < 4; r++)
                o[jjo][r] *= alpha[r];

        // P -> LDS transpose (kt-parity buffer; compiler tracks the dep)
#pragma unroll
        for (int jj = 0; jj < 4; jj++)
#pragma unroll
            for (int r = 0; r < 4; r++)
                Pl[wave][kt][(g * 4 + r) * 68 + jj * 16 + c] = f2b(s[jj][r]);

        short8 pa[2];
#pragma unroll
        for (int ks = 0; ks < 2; ks++)
            pa[ks] = *(const short8*)&Pl[wave][kt][c * 68 + ks * 32 + g * 8];
        __builtin_amdgcn_s_setprio(1);
#pragma unroll
        for (int jjo = 0; jjo < 4; jjo++)
#pragma unroll
            for (int ks = 0; ks < 2; ks++)
                o[jjo] = __builtin_amdgcn_mfma_f32_16x16x32_bf16(pa[ks], vf[jjo][ks], o[jjo], 0, 0, 0);
        __builtin_amdgcn_s_setprio(0);
    }

    if (wave > 0) {
#pragma unroll
        for (int r = 0; r < 4; r++) {
            Mrg[wave - 1][lane][r] = m[r];
            Mrg[wave - 1][lane][4 + r] = l[r];
#pragma unroll
            for (int jjo = 0; jjo < 4; jjo++)
                Mrg[wave - 1][lane][8 + jjo * 4 + r] = o[jjo][r];
        }
    }
    __syncthreads();
    if (wave == 0) {
#pragma unroll
        for (int w = 0; w < 3; w++) {
#pragma unroll
            for (int r = 0; r < 4; r++) {
                float m1 = Mrg[w][lane][r];
                float l1 = Mrg[w][lane][4 + r];
                float mn = fmaxf(m[r], m1);
                float a0 = __expf(m[r] - mn), a1 = __expf(m1 - mn);
                m[r] = mn;
                l[r] = l[r] * a0 + l1 * a1;
#pragma unroll
                for (int jjo = 0; jjo < 4; jjo++)
                    o[jjo][r] = o[jjo][r] * a0 + Mrg[w][lane][8 + jjo * 4 + r] * a1;
            }
        }
#pragma unroll
        for (int r = 0; r < 4; r++) {
            float inv = 1.0f / l[r];
            int row = q0 + g * 4 + r;
#pragma unroll
            for (int jjo = 0; jjo < 4; jjo++)
                ATT[(size_t)(((b << 9) + row) << 9) + (h << 6) + jjo * 16 + c] = f2b(o[jjo][r] * inv);
        }
    }
}

// ---------- merged projection GEMM (dbuf counted-vmcnt staging) ----------
__global__ __launch_bounds__(256) void proj_k(const u16* __restrict__ Xall,
                                              const u16* __restrict__ Wall,
                                              const float* __restrict__ bq,
                                              const float* __restrict__ bk,
                                              const float* __restrict__ bv,
                                              u16* __restrict__ Qb,
                                              u16* __restrict__ Kb,
                                              u16* __restrict__ VT) {
    __shared__ u16 As[2][64 * 32];
    __shared__ u16 Bs[2][64 * 32];

    const int t = threadIdx.x;
    const int wave = t >> 6, lane = t & 63;
    const int wr = wave >> 1, wc = wave & 1;
    const int m0 = blockIdx.y * 64, n0 = blockIdx.x * 64;
    const int z = blockIdx.z;

    const u16* A  = Xall + (size_t)z * 1048576;
    const u16* Bm = Wall + (size_t)z * 262144;
    const float* bias = (z == 0) ? bq : (z == 1) ? bk : bv;
    u16* out = (z == 0) ? Qb : (z == 1) ? Kb : VT;

    f32x4 acc[2][2] = {};
    const int srow = t >> 2;
    const int scol = (((t & 3) ^ ((t >> 3) & 3)) << 3);
    const int c = lane & 15, g = lane >> 4;
    const int gsw = (g ^ ((c >> 1) & 3)) << 3;

    const size_t arow = (size_t)(m0 + srow) * 512 + scol;
    const size_t brow = (size_t)(n0 + srow) * 512 + scol;

    gload_lds16(&A[arow], &As[0][t * 8]);
    gload_lds16(&Bm[brow], &Bs[0][t * 8]);

    int cur = 0;
    for (int k0 = 0; k0 < 512; k0 += 32, cur ^= 1) {
        if (k0 + 32 < 512) {
            gload_lds16(&A[arow + k0 + 32], &As[cur ^ 1][t * 8]);
            gload_lds16(&Bm[brow + k0 + 32], &Bs[cur ^ 1][t * 8]);
            asm volatile("s_waitcnt vmcnt(2)" ::: "memory");
        } else {
            asm volatile("s_waitcnt vmcnt(0)" ::: "memory");
        }
        __builtin_amdgcn_s_barrier();
        __builtin_amdgcn_sched_barrier(0);
        short8 af[2], bfr[2];
#pragma unroll
        for (int i = 0; i < 2; i++)
            af[i] = *(const short8*)&As[cur][(wr * 32 + i * 16 + c) * 32 + gsw];
#pragma unroll
        for (int jj = 0; jj < 2; jj++)
            bfr[jj] = *(const short8*)&Bs[cur][(wc * 32 + jj * 16 + c) * 32 + gsw];
#pragma unroll
        for (int i = 0; i < 2; i++)
#pragma unroll
            for (int jj = 0; jj < 2; jj++)
                acc[i][jj] = __builtin_amdgcn_mfma_f32_16x16x32_bf16(af[i], bfr[jj], acc[i][jj], 0, 0, 0);
        __builtin_amdgcn_sched_barrier(0);
        __builtin_amdgcn_s_barrier();
    }

#pragma unroll
    for (int i = 0; i < 2; i++)
#pragma unroll
        for (int jj = 0; jj < 2; jj++)
#pragma unroll
            for (int r = 0; r < 4; r++) {
                int row = m0 + wr * 32 + i * 16 + ((lane >> 4) << 2) + r;
                int col = n0 + wc * 32 + jj * 16 + (lane & 15);
                float v = acc[i][jj][r] + bias[col];
                int b = row >> 9, rr = row & 511, h = col >> 6, d = col & 63;
                if (z < 2)
                    out[(size_t)((((b << 3) + h) << 9) + rr) * 64 + d] = f2b(v);
                else
                    out[(size_t)((((b << 3) + h) << 6) + d) * 512 + rr] = f2b(v);
            }
}

// ---------- output GEMM (dbuf staging) ----------
__global__ __launch_bounds__(256) void outg_k(const u16* __restrict__ A,
                                              const u16* __restrict__ Bm,
                                              const float* __restrict__ bias,
                                              float* __restrict__ outF) {
    __shared__ u16 As[2][64 * 32];
    __shared__ u16 Bs[2][64 * 32];

    const int t = threadIdx.x;
    const int wave = t >> 6, lane = t & 63;
    const int wr = wave >> 1, wc = wave & 1;
    const int m0 = blockIdx.y * 64, n0 = blockIdx.x * 64;

    f32x4 acc[2][2] = {};
    const int srow = t >> 2;
    const int scol = (((t & 3) ^ ((t >> 3) & 3)) << 3);
    const int c = lane & 15, g = lane >> 4;
    const int gsw = (g ^ ((c >> 1) & 3)) << 3;

    const size_t arow = (size_t)(m0 + srow) * 512 + scol;
    const size_t brow = (size_t)(n0 + srow) * 512 + scol;

    gload_lds16(&A[arow], &As[0][t * 8]);
    gload_lds16(&Bm[brow], &Bs[0][t * 8]);

    int cur = 0;
    for (int k0 = 0; k0 < 512; k0 += 32, cur ^= 1) {
        if (k0 + 32 < 512) {
            gload_lds16(&A[arow + k0 + 32], &As[cur ^ 1][t * 8]);
            gload_lds16(&Bm[brow + k0 + 32], &Bs[cur ^ 1][t * 8]);
            asm volatile("s_waitcnt vmcnt(2)" ::: "memory");
        } else {
            asm volatile("s_waitcnt vmcnt(0)" ::: "memory");
        }
        __builtin_amdgcn_s_barrier();
        __builtin_amdgcn_sched_barrier(0);
        short8 af[2], bfr[2];
#pragma unroll
        for (int i = 0; i < 2; i++)
            af[i] = *(const short8*)&As[cur][(wr * 32 + i * 16 + c) * 32 + gsw];
#pragma unroll
        for (int jj = 0; jj < 2; jj++)
            bfr[jj] = *(const short8*)&Bs[cur][(wc * 32 + jj * 16 + c) * 32 + gsw];
#pragma unroll
        for (int i = 0; i < 2; i++)
#pragma unroll
            for (int jj = 0; jj < 2; jj++)
                acc[i][jj] = __builtin_amdgcn_mfma_f32_16x16x32_bf16(af[i], bfr[jj], acc[i][jj], 0, 0, 0);
        __builtin_amdgcn_sched_barrier(0);
        __builtin_amdgcn_s_barrier();
    }

#pragma unroll
    for (int i = 0; i < 2; i++)
#pragma unroll
        for (int jj = 0; jj < 2; jj++)
#pragma unroll
            for (int r = 0; r < 4; r++) {
                int row = m0 + wr * 32 + i * 16 + ((lane >> 4) << 2) + r;
                int col = n0 + wc * 32 + jj * 16 + (lane & 15);
                outF[((size_t)row << 9) + col] = acc[i][jj][r] + bias[col];
            }
}

// ---------- launch ----------
extern "C" void kernel_launch(void* const* d_in, const int* in_sizes, int n_in,
                              void* d_out, int out_size, void* d_ws, size_t ws_size,
                              hipStream_t stream) {
    const float* inq = (const float*)d_in[0];
    const float* ink = (const float*)d_in[1];
    const float* inv = (const float*)d_in[2];
    const float* box = (const float*)d_in[3];
    const float* Wq  = (const float*)d_in[4];
    const float* bq  = (const float*)d_in[5];
    const float* Wk  = (const float*)d_in[6];
    const float* bk  = (const float*)d_in[7];
    const float* Wv  = (const float*)d_in[8];
    const float* bv  = (const float*)d_in[9];
    const float* Wo  = (const float*)d_in[10];
    const float* bo  = (const float*)d_in[11];
    const float* WG  = (const float*)d_in[12];
    const float* bG  = (const float*)d_in[13];

    u16* base = (u16*)d_ws;
    u16* Xall = base;                    // XQ,XK,XV bf16 (3 x 1,048,576)
    u16* Wall = base + 3145728;          // WQb,WKb,WVb,WOb bf16 (4 x 262,144)
    u16* Qb   = base + 4194304;          // [B,H,N,64] bf16
    u16* Kb   = base + 5242880;          // [B,H,N,64] bf16
    u16* VT   = base + 6291456;          // [B,H,64,N] bf16
    u16* ATT  = base + 7340032;          // [B,N,512] bf16
    u16* Wp   = base + 8388608;          // [B,H,N,N] f16 geometry weights

    prep_k<<<dim3(1024, 1, 11), 256, 0, stream>>>(inq, ink, inv, Wq, Wk, Wv, Wo,
                                                  box, WG, bG, Xall, Wall, Wp);

    proj_k<<<dim3(8, 32, 3), 256, 0, stream>>>(Xall, Wall, bq, bk, bv, Qb, Kb, VT);

    attn_k<<<dim3(1024), 256, 0, stream>>>(Qb, Kb, VT, Wp, ATT);

    outg_k<<<dim3(8, 32, 1), 256, 0, stream>>>(ATT, Wall + 786432, bo, (float*)d_out);
}

// Round 15
// 70.087 us; speedup vs baseline: 6.3974x; 1.0504x over previous
//
#include <hip/hip_runtime.h>
#include <hip/hip_bf16.h>
#include <cstdint>

typedef unsigned short u16;
typedef unsigned int u32;
typedef __attribute__((ext_vector_type(8))) short short8;   // 8 bf16 MFMA A/B frag
typedef __attribute__((ext_vector_type(4))) float f32x4;    // MFMA C/D frag
typedef __attribute__((ext_vector_type(4))) unsigned int u32x4;
typedef __attribute__((ext_vector_type(4))) unsigned short u16x4;

#define REV 15.91549431f   // 100/(2*pi): the "100*pos" angle in revolutions

// ---------- helpers ----------
__device__ __forceinline__ u16 f2b(float x) { return __builtin_bit_cast(u16, (__bf16)x); }
__device__ __forceinline__ u16 f2h(float x) { return __builtin_bit_cast(u16, (_Float16)x); }
__device__ __forceinline__ float c_dim_f(int f) {
    const float c[8] = {1.0f, 0.42169650f, 0.17782794f, 0.074989421f,
                        0.031622777f, 0.013335214f, 0.0056234132f, 0.0023713737f};
    return c[f];
}
__device__ __forceinline__ void gload_lds16(const void* g, void* l) {
    __builtin_amdgcn_global_load_lds((const __attribute__((address_space(1))) u32*)g,
                                     (__attribute__((address_space(3))) u32*)l, 16, 0, 0);
}

// ---------- prep: f32->bf16 cvt (z 0..6) + geometry weights (z 7..10) ----------
// Geometry: each block now handles 4 units (2 i x 2 jt) so the WG-fragment
// setup / bj loads / i-side logs are amortized 4x/2x across units. Per-pair
// math is unchanged (bit-identical output).
__global__ __launch_bounds__(256) void prep_k(const float* __restrict__ s0,
                                              const float* __restrict__ s1,
                                              const float* __restrict__ s2,
                                              const float* __restrict__ s3,
                                              const float* __restrict__ s4,
                                              const float* __restrict__ s5,
                                              const float* __restrict__ s6,
                                              const float* __restrict__ box,
                                              const float* __restrict__ WG,
                                              const float* __restrict__ bG,
                                              u16* __restrict__ dstX,
                                              u16* __restrict__ dstW,
                                              u16* __restrict__ outW) {
    __shared__ char embs[256 * 128];   // [256 pairs][64 bf16] rows, 128B each
    const int z = blockIdx.z;
    const int t = threadIdx.x;

    if (z < 7) {
        const float* s;
        u16* dst;
        if (z < 3) {
            s = (z == 0) ? s0 : (z == 1) ? s1 : s2;
            dst = dstX + (size_t)z * 1048576;
        } else {
            if (blockIdx.x >= 256) return;
            s = (z == 3) ? s3 : (z == 4) ? s4 : (z == 5) ? s5 : s6;
            dst = dstW + (size_t)(z - 3) * 262144;
        }
        int i = (blockIdx.x * 256 + t) * 4;
        float4 v = *(const float4*)&s[i];
        u16x4 o = { f2b(v.x), f2b(v.y), f2b(v.z), f2b(v.w) };
        *(u16x4*)&dst[i] = o;
        return;
    }

    // ---------------- geometry: 4 units per block ----------------
    if (blockIdx.x >= 256) return;
    const int wave = t >> 6, lane = t & 63;
    const int b = z - 7;
    const int ipair = blockIdx.x;          // i = 2*ipair, 2*ipair+1
    const int swz = (t & 7) << 4;

    // i-side (block-uniform), hoisted for both i's
    float cxi[2], cyi[2], wdi[2], hgi[2], lwi[2], lhi[2];
#pragma unroll
    for (int iu = 0; iu < 2; iu++) {
        int ii = (ipair << 1) + iu;
        float4 bi = *(const float4*)&box[(size_t)(((b << 9) + ii) << 2)];
        cxi[iu] = (bi.x + bi.z) * 0.5f; cyi[iu] = (bi.y + bi.w) * 0.5f;
        wdi[iu] = bi.z - bi.x + 1.0f;   hgi[iu] = bi.w - bi.y + 1.0f;
        lwi[iu] = __logf(wdi[iu]);      lhi[iu] = __logf(hgi[iu]);
    }

    // WG fragments, hoisted once per wave
    const int hh = lane & 15;
    const int ko = (lane >> 4) << 3;
    short8 bf0 = {0,0,0,0,0,0,0,0}, bf1 = {0,0,0,0,0,0,0,0};
    float bGh = 0.0f;
    if (hh < 8) {
        const float* wrow = WG + hh * 64;
#pragma unroll
        for (int e = 0; e < 8; e++) {
            bf0[e] = (short)f2b(wrow[ko + e]);
            bf1[e] = (short)f2b(wrow[32 + ko + e]);
        }
        bGh = bG[hh];
    }

    for (int jt = 0; jt < 2; jt++) {
        const int j = (jt << 8) + t;
        float4 bj = *(const float4*)&box[(size_t)(((b << 9) + j) << 2)];
        float cxj = (bj.x + bj.z) * 0.5f, cyj = (bj.y + bj.w) * 0.5f;
        float wdj = bj.z - bj.x + 1.0f,   hgj = bj.w - bj.y + 1.0f;
        float lwj = __logf(wdj), lhj = __logf(hgj);

#pragma unroll
        for (int iu = 0; iu < 2; iu++) {
            const int ii = (ipair << 1) + iu;
            float pos[4];
            pos[0] = __logf(fmaxf(fabsf((cxi[iu] - cxj) / wdi[iu]), 1e-3f));
            pos[1] = __logf(fmaxf(fabsf((cyi[iu] - cyj) / hgi[iu]), 1e-3f));
            pos[2] = lwi[iu] - lwj;
            pos[3] = lhi[iu] - lhj;

#pragma unroll
            for (int p = 0; p < 4; p++) {
                float rev = pos[p] * REV;
                u32x4 sp, cp;
#pragma unroll
                for (int f = 0; f < 4; f++) {
                    float a0 = rev * c_dim_f(2 * f), a1 = rev * c_dim_f(2 * f + 1);
                    sp[f] = (u32)f2b(__builtin_amdgcn_sinf(a0)) | ((u32)f2b(__builtin_amdgcn_sinf(a1)) << 16);
                    cp[f] = (u32)f2b(__builtin_amdgcn_cosf(a0)) | ((u32)f2b(__builtin_amdgcn_cosf(a1)) << 16);
                }
                *(u32x4*)(embs + (((t << 7) + (p << 4)) ^ swz)) = sp;
                *(u32x4*)(embs + (((t << 7) + 64 + (p << 4)) ^ swz)) = cp;
            }
            __syncthreads();

#pragma unroll
            for (int tt = 0; tt < 4; tt++) {
                int mt = (wave << 2) + tt;
                int row = (mt << 4) + hh;
                int rswz = (row & 7) << 4;
                short8 a0v = *(const short8*)(embs + (((row << 7) + (ko << 1)) ^ rswz));
                short8 a1v = *(const short8*)(embs + (((row << 7) + 64 + (ko << 1)) ^ rswz));
                f32x4 acc = {0.f, 0.f, 0.f, 0.f};
                acc = __builtin_amdgcn_mfma_f32_16x16x32_bf16(a0v, bf0, acc, 0, 0, 0);
                acc = __builtin_amdgcn_mfma_f32_16x16x32_bf16(a1v, bf1, acc, 0, 0, 0);
                if (hh < 8) {
                    int j0 = (jt << 8) + (mt << 4) + ((lane >> 4) << 2);
                    u16x4 ow;
#pragma unroll
                    for (int r = 0; r < 4; r++)
                        ow[r] = f2h(fmaxf(acc[r] + bGh, 1e-6f) * 1024.0f);
                    *(u16x4*)&outW[((size_t)((b << 3) + hh) << 18) + ((size_t)ii << 9) + j0] = ow;
                }
            }
            __syncthreads();   // embs reused by next unit
        }
    }
}

// ---------- fused flash attention (R12 version): p = w*e^(0.125*QK^T - m) ----------
__global__ __launch_bounds__(256) void attn_k(const u16* __restrict__ Qb,
                                              const u16* __restrict__ Kb,
                                              const u16* __restrict__ VT,
                                              const u16* __restrict__ Wp,
                                              u16* __restrict__ ATT) {
    __shared__ u16 Pl[4][16 * 68];
    __shared__ float Mrg[3][64][25];
    const int t = threadIdx.x;
    const int wave = t >> 6, lane = t & 63;
    const int c = lane & 15, g = lane >> 4;
    const int bid = blockIdx.x;
    const int qb = bid & 31, bh = bid >> 5;
    const int b = bh >> 3, h = bh & 7;
    const int q0 = qb << 4;

    const u16* Qp = Qb + ((size_t)bh << 15);
    const u16* Kp = Kb + ((size_t)bh << 15);
    const u16* Vp = VT + ((size_t)bh << 15);
    const _Float16* Bp = (const _Float16*)Wp + ((size_t)bh << 18) + ((size_t)q0 << 9);

    short8 qf[2];
#pragma unroll
    for (int ks = 0; ks < 2; ks++)
        qf[ks] = *(const short8*)&Qp[(size_t)(q0 + c) * 64 + ks * 32 + g * 8];

    f32x4 o[4] = {};
    float m[4] = {-1e30f, -1e30f, -1e30f, -1e30f};
    float l[4] = {0.f, 0.f, 0.f, 0.f};

    for (int kt = 0; kt < 2; kt++) {
        const int k0 = ((wave << 1) + kt) << 6;
        short8 kf[4][2], vf[4][2];
#pragma unroll
        for (int jj = 0; jj < 4; jj++)
#pragma unroll
            for (int ks = 0; ks < 2; ks++) {
                kf[jj][ks] = *(const short8*)&Kp[(size_t)(k0 + jj * 16 + c) * 64 + ks * 32 + g * 8];
                vf[jj][ks] = *(const short8*)&Vp[(size_t)(jj * 16 + c) * 512 + k0 + ks * 32 + g * 8];
            }
        float wgt[4][4];
#pragma unroll
        for (int jj = 0; jj < 4; jj++)
#pragma unroll
            for (int r = 0; r < 4; r++)
                wgt[jj][r] = (float)Bp[(size_t)(g * 4 + r) * 512 + k0 + jj * 16 + c];

        f32x4 sa[4] = {};
        __builtin_amdgcn_s_setprio(1);
#pragma unroll
        for (int jj = 0; jj < 4; jj++)
#pragma unroll
            for (int ks = 0; ks < 2; ks++)
                sa[jj] = __builtin_amdgcn_mfma_f32_16x16x32_bf16(qf[ks], kf[jj][ks], sa[jj], 0, 0, 0);
        __builtin_amdgcn_s_setprio(0);

        float s[4][4];
#pragma unroll
        for (int r = 0; r < 4; r++) {
#pragma unroll
            for (int jj = 0; jj < 4; jj++)
                s[jj][r] = sa[jj][r] * 0.125f;
            float v = fmaxf(fmaxf(s[0][r], s[1][r]), fmaxf(s[2][r], s[3][r]));
#pragma unroll
            for (int off = 1; off < 16; off <<= 1)
                v = fmaxf(v, __shfl_xor(v, off));
            float mn = fmaxf(m[r], v);
            float alpha = __expf(m[r] - mn);
            m[r] = mn;
            float rs = 0.f;
#pragma unroll
            for (int jj = 0; jj < 4; jj++) {
                float p = wgt[jj][r] * __expf(s[jj][r] - mn);
                s[jj][r] = p;
                rs += p;
            }
#pragma unroll
            for (int off = 1; off < 16; off <<= 1)
                rs += __shfl_xor(rs, off);
            l[r] = l[r] * alpha + rs;
#pragma unroll
            for (int jjo = 0; jjo < 4; jjo++)
                o[jjo][r] *= alpha;
        }

#pragma unroll
        for (int jj = 0; jj < 4; jj++)
#pragma unroll
            for (int r = 0; r < 4; r++)
                Pl[wave][(g * 4 + r) * 68 + jj * 16 + c] = f2b(s[jj][r]);
        asm volatile("s_waitcnt lgkmcnt(0)" ::: "memory");
        __builtin_amdgcn_sched_barrier(0);

        short8 pa[2];
#pragma unroll
        for (int ks = 0; ks < 2; ks++)
            pa[ks] = *(const short8*)&Pl[wave][c * 68 + ks * 32 + g * 8];
        __builtin_amdgcn_s_setprio(1);
#pragma unroll
        for (int jjo = 0; jjo < 4; jjo++)
#pragma unroll
            for (int ks = 0; ks < 2; ks++)
                o[jjo] = __builtin_amdgcn_mfma_f32_16x16x32_bf16(pa[ks], vf[jjo][ks], o[jjo], 0, 0, 0);
        __builtin_amdgcn_s_setprio(0);
        __builtin_amdgcn_sched_barrier(0);
    }

    if (wave > 0) {
#pragma unroll
        for (int r = 0; r < 4; r++) {
            Mrg[wave - 1][lane][r] = m[r];
            Mrg[wave - 1][lane][4 + r] = l[r];
#pragma unroll
            for (int jjo = 0; jjo < 4; jjo++)
                Mrg[wave - 1][lane][8 + jjo * 4 + r] = o[jjo][r];
        }
    }
    __syncthreads();
    if (wave == 0) {
#pragma unroll
        for (int w = 0; w < 3; w++) {
#pragma unroll
            for (int r = 0; r < 4; r++) {
                float m1 = Mrg[w][lane][r];
                float l1 = Mrg[w][lane][4 + r];
                float mn = fmaxf(m[r], m1);
                float a0 = __expf(m[r] - mn), a1 = __expf(m1 - mn);
                m[r] = mn;
                l[r] = l[r] * a0 + l1 * a1;
#pragma unroll
                for (int jjo = 0; jjo < 4; jjo++)
                    o[jjo][r] = o[jjo][r] * a0 + Mrg[w][lane][8 + jjo * 4 + r] * a1;
            }
        }
#pragma unroll
        for (int r = 0; r < 4; r++) {
            float inv = 1.0f / l[r];
            int row = q0 + g * 4 + r;
#pragma unroll
            for (int jjo = 0; jjo < 4; jjo++)
                ATT[(size_t)(((b << 9) + row) << 9) + (h << 6) + jjo * 16 + c] = f2b(o[jjo][r] * inv);
        }
    }
}

// ---------- merged projection GEMM (dbuf counted-vmcnt staging) ----------
__global__ __launch_bounds__(256) void proj_k(const u16* __restrict__ Xall,
                                              const u16* __restrict__ Wall,
                                              const float* __restrict__ bq,
                                              const float* __restrict__ bk,
                                              const float* __restrict__ bv,
                                              u16* __restrict__ Qb,
                                              u16* __restrict__ Kb,
                                              u16* __restrict__ VT) {
    __shared__ u16 As[2][64 * 32];
    __shared__ u16 Bs[2][64 * 32];

    const int t = threadIdx.x;
    const int wave = t >> 6, lane = t & 63;
    const int wr = wave >> 1, wc = wave & 1;
    const int m0 = blockIdx.y * 64, n0 = blockIdx.x * 64;
    const int z = blockIdx.z;

    const u16* A  = Xall + (size_t)z * 1048576;
    const u16* Bm = Wall + (size_t)z * 262144;
    const float* bias = (z == 0) ? bq : (z == 1) ? bk : bv;
    u16* out = (z == 0) ? Qb : (z == 1) ? Kb : VT;

    f32x4 acc[2][2] = {};
    const int srow = t >> 2;
    const int scol = (((t & 3) ^ ((t >> 3) & 3)) << 3);
    const int c = lane & 15, g = lane >> 4;
    const int gsw = (g ^ ((c >> 1) & 3)) << 3;

    const size_t arow = (size_t)(m0 + srow) * 512 + scol;
    const size_t brow = (size_t)(n0 + srow) * 512 + scol;

    gload_lds16(&A[arow], &As[0][t * 8]);
    gload_lds16(&Bm[brow], &Bs[0][t * 8]);

    int cur = 0;
    for (int k0 = 0; k0 < 512; k0 += 32, cur ^= 1) {
        if (k0 + 32 < 512) {
            gload_lds16(&A[arow + k0 + 32], &As[cur ^ 1][t * 8]);
            gload_lds16(&Bm[brow + k0 + 32], &Bs[cur ^ 1][t * 8]);
            asm volatile("s_waitcnt vmcnt(2)" ::: "memory");
        } else {
            asm volatile("s_waitcnt vmcnt(0)" ::: "memory");
        }
        __builtin_amdgcn_s_barrier();
        __builtin_amdgcn_sched_barrier(0);
        short8 af[2], bfr[2];
#pragma unroll
        for (int i = 0; i < 2; i++)
            af[i] = *(const short8*)&As[cur][(wr * 32 + i * 16 + c) * 32 + gsw];
#pragma unroll
        for (int jj = 0; jj < 2; jj++)
            bfr[jj] = *(const short8*)&Bs[cur][(wc * 32 + jj * 16 + c) * 32 + gsw];
#pragma unroll
        for (int i = 0; i < 2; i++)
#pragma unroll
            for (int jj = 0; jj < 2; jj++)
                acc[i][jj] = __builtin_amdgcn_mfma_f32_16x16x32_bf16(af[i], bfr[jj], acc[i][jj], 0, 0, 0);
        __builtin_amdgcn_sched_barrier(0);
        __builtin_amdgcn_s_barrier();
    }

#pragma unroll
    for (int i = 0; i < 2; i++)
#pragma unroll
        for (int jj = 0; jj < 2; jj++)
#pragma unroll
            for (int r = 0; r < 4; r++) {
                int row = m0 + wr * 32 + i * 16 + ((lane >> 4) << 2) + r;
                int col = n0 + wc * 32 + jj * 16 + (lane & 15);
                float v = acc[i][jj][r] + bias[col];
                int b = row >> 9, rr = row & 511, h = col >> 6, d = col & 63;
                if (z < 2)
                    out[(size_t)((((b << 3) + h) << 9) + rr) * 64 + d] = f2b(v);
                else
                    out[(size_t)((((b << 3) + h) << 6) + d) * 512 + rr] = f2b(v);
            }
}

// ---------- output GEMM (dbuf staging) ----------
__global__ __launch_bounds__(256) void outg_k(const u16* __restrict__ A,
                                              const u16* __restrict__ Bm,
                                              const float* __restrict__ bias,
                                              float* __restrict__ outF) {
    __shared__ u16 As[2][64 * 32];
    __shared__ u16 Bs[2][64 * 32];

    const int t = threadIdx.x;
    const int wave = t >> 6, lane = t & 63;
    const int wr = wave >> 1, wc = wave & 1;
    const int m0 = blockIdx.y * 64, n0 = blockIdx.x * 64;

    f32x4 acc[2][2] = {};
    const int srow = t >> 2;
    const int scol = (((t & 3) ^ ((t >> 3) & 3)) << 3);
    const int c = lane & 15, g = lane >> 4;
    const int gsw = (g ^ ((c >> 1) & 3)) << 3;

    const size_t arow = (size_t)(m0 + srow) * 512 + scol;
    const size_t brow = (size_t)(n0 + srow) * 512 + scol;

    gload_lds16(&A[arow], &As[0][t * 8]);
    gload_lds16(&Bm[brow], &Bs[0][t * 8]);

    int cur = 0;
    for (int k0 = 0; k0 < 512; k0 += 32, cur ^= 1) {
        if (k0 + 32 < 512) {
            gload_lds16(&A[arow + k0 + 32], &As[cur ^ 1][t * 8]);
            gload_lds16(&Bm[brow + k0 + 32], &Bs[cur ^ 1][t * 8]);
            asm volatile("s_waitcnt vmcnt(2)" ::: "memory");
        } else {
            asm volatile("s_waitcnt vmcnt(0)" ::: "memory");
        }
        __builtin_amdgcn_s_barrier();
        __builtin_amdgcn_sched_barrier(0);
        short8 af[2], bfr[2];
#pragma unroll
        for (int i = 0; i < 2; i++)
            af[i] = *(const short8*)&As[cur][(wr * 32 + i * 16 + c) * 32 + gsw];
#pragma unroll
        for (int jj = 0; jj < 2; jj++)
            bfr[jj] = *(const short8*)&Bs[cur][(wc * 32 + jj * 16 + c) * 32 + gsw];
#pragma unroll
        for (int i = 0; i < 2; i++)
#pragma unroll
            for (int jj = 0; jj < 2; jj++)
                acc[i][jj] = __builtin_amdgcn_mfma_f32_16x16x32_bf16(af[i], bfr[jj], acc[i][jj], 0, 0, 0);
        __builtin_amdgcn_sched_barrier(0);
        __builtin_amdgcn_s_barrier();
    }

#pragma unroll
    for (int i = 0; i < 2; i++)
#pragma unroll
        for (int jj = 0; jj < 2; jj++)
#pragma unroll
            for (int r = 0; r < 4; r++) {
                int row = m0 + wr * 32 + i * 16 + ((lane >> 4) << 2) + r;
                int col = n0 + wc * 32 + jj * 16 + (lane & 15);
                outF[((size_t)row << 9) + col] = acc[i][jj][r] + bias[col];
            }
}

// ---------- launch ----------
extern "C" void kernel_launch(void* const* d_in, const int* in_sizes, int n_in,
                              void* d_out, int out_size, void* d_ws, size_t ws_size,
                              hipStream_t stream) {
    const float* inq = (const float*)d_in[0];
    const float* ink = (const float*)d_in[1];
    const float* inv = (const float*)d_in[2];
    const float* box = (const float*)d_in[3];
    const float* Wq  = (const float*)d_in[4];
    const float* bq  = (const float*)d_in[5];
    const float* Wk  = (const float*)d_in[6];
    const float* bk  = (const float*)d_in[7];
    const float* Wv  = (const float*)d_in[8];
    const float* bv  = (const float*)d_in[9];
    const float* Wo  = (const float*)d_in[10];
    const float* bo  = (const float*)d_in[11];
    const float* WG  = (const float*)d_in[12];
    const float* bG  = (const float*)d_in[13];

    u16* base = (u16*)d_ws;
    u16* Xall = base;                    // XQ,XK,XV bf16 (3 x 1,048,576)
    u16* Wall = base + 3145728;          // WQb,WKb,WVb,WOb bf16 (4 x 262,144)
    u16* Qb   = base + 4194304;          // [B,H,N,64] bf16
    u16* Kb   = base + 5242880;          // [B,H,N,64] bf16
    u16* VT   = base + 6291456;          // [B,H,64,N] bf16
    u16* ATT  = base + 7340032;          // [B,N,512] bf16
    u16* Wp   = base + 8388608;          // [B,H,N,N] f16 geometry weights

    prep_k<<<dim3(1024, 1, 11), 256, 0, stream>>>(inq, ink, inv, Wq, Wk, Wv, Wo,
                                                  box, WG, bG, Xall, Wall, Wp);

    proj_k<<<dim3(8, 32, 3), 256, 0, stream>>>(Xall, Wall, bq, bk, bv, Qb, Kb, VT);

    attn_k<<<dim3(1024), 256, 0, stream>>>(Qb, Kb, VT, Wp, ATT);

    outg_k<<<dim3(8, 32, 1), 256, 0, stream>>>(ATT, Wall + 786432, bo, (float*)d_out);
}

// Round 17
// 68.952 us; speedup vs baseline: 6.5027x; 1.0165x over previous
//
#include <hip/hip_runtime.h>
#include <hip/hip_bf16.h>
#include <cstdint>

typedef unsigned short u16;
typedef unsigned int u32;
typedef __attribute__((ext_vector_type(8))) short short8;   // 8 bf16 MFMA A/B frag
typedef __attribute__((ext_vector_type(4))) float f32x4;    // MFMA C/D frag
typedef __attribute__((ext_vector_type(4))) unsigned int u32x4;
typedef __attribute__((ext_vector_type(4))) unsigned short u16x4;

#define REV 15.91549431f   // 100/(2*pi): the "100*pos" angle in revolutions

// ---------- helpers ----------
__device__ __forceinline__ u16 f2b(float x) { return __builtin_bit_cast(u16, (__bf16)x); }
__device__ __forceinline__ u16 f2h(float x) { return __builtin_bit_cast(u16, (_Float16)x); }
__device__ __forceinline__ float c_dim_f(int f) {
    const float c[8] = {1.0f, 0.42169650f, 0.17782794f, 0.074989421f,
                        0.031622777f, 0.013335214f, 0.0056234132f, 0.0023713737f};
    return c[f];
}
__device__ __forceinline__ void gload_lds16(const void* g, void* l) {
    __builtin_amdgcn_global_load_lds((const __attribute__((address_space(1))) u32*)g,
                                     (__attribute__((address_space(3))) u32*)l, 16, 0, 0);
}

// ---------- prep: f32->bf16 cvt (z 0..6, needs 1024 x-blocks) ----------
// ----------       geometry weights (z 7..10, first 256 x-blocks) --------
// Geometry: 4 units per block (2 i x 2 jt). w = 1024*max(relu(emb@WG+bG),1e-6)
// stored f16 (consumed multiplicatively: softmax(log(w)+s) == norm. w*e^s).
__global__ __launch_bounds__(256) void prep_k(const float* __restrict__ s0,
                                              const float* __restrict__ s1,
                                              const float* __restrict__ s2,
                                              const float* __restrict__ s3,
                                              const float* __restrict__ s4,
                                              const float* __restrict__ s5,
                                              const float* __restrict__ s6,
                                              const float* __restrict__ box,
                                              const float* __restrict__ WG,
                                              const float* __restrict__ bG,
                                              u16* __restrict__ dstX,
                                              u16* __restrict__ dstW,
                                              u16* __restrict__ outW) {
    __shared__ char embs[256 * 128];   // [256 pairs][64 bf16] rows, 128B each
    const int z = blockIdx.z;
    const int t = threadIdx.x;

    if (z < 7) {
        const float* s;
        u16* dst;
        if (z < 3) {
            s = (z == 0) ? s0 : (z == 1) ? s1 : s2;
            dst = dstX + (size_t)z * 1048576;
        } else {
            if (blockIdx.x >= 256) return;
            s = (z == 3) ? s3 : (z == 4) ? s4 : (z == 5) ? s5 : s6;
            dst = dstW + (size_t)(z - 3) * 262144;
        }
        int i = (blockIdx.x * 256 + t) * 4;
        float4 v = *(const float4*)&s[i];
        u16x4 o = { f2b(v.x), f2b(v.y), f2b(v.z), f2b(v.w) };
        *(u16x4*)&dst[i] = o;
        return;
    }

    // ---------------- geometry: 4 units per block ----------------
    if (blockIdx.x >= 256) return;
    const int wave = t >> 6, lane = t & 63;
    const int b = z - 7;
    const int ipair = blockIdx.x;          // i = 2*ipair, 2*ipair+1
    const int swz = (t & 7) << 4;

    float cxi[2], cyi[2], wdi[2], hgi[2], lwi[2], lhi[2];
#pragma unroll
    for (int iu = 0; iu < 2; iu++) {
        int ii = (ipair << 1) + iu;
        float4 bi = *(const float4*)&box[(size_t)(((b << 9) + ii) << 2)];
        cxi[iu] = (bi.x + bi.z) * 0.5f; cyi[iu] = (bi.y + bi.w) * 0.5f;
        wdi[iu] = bi.z - bi.x + 1.0f;   hgi[iu] = bi.w - bi.y + 1.0f;
        lwi[iu] = __logf(wdi[iu]);      lhi[iu] = __logf(hgi[iu]);
    }

    const int hh = lane & 15;
    const int ko = (lane >> 4) << 3;
    short8 bf0 = {0,0,0,0,0,0,0,0}, bf1 = {0,0,0,0,0,0,0,0};
    float bGh = 0.0f;
    if (hh < 8) {
        const float* wrow = WG + hh * 64;
#pragma unroll
        for (int e = 0; e < 8; e++) {
            bf0[e] = (short)f2b(wrow[ko + e]);
            bf1[e] = (short)f2b(wrow[32 + ko + e]);
        }
        bGh = bG[hh];
    }

    for (int jt = 0; jt < 2; jt++) {
        const int j = (jt << 8) + t;
        float4 bj = *(const float4*)&box[(size_t)(((b << 9) + j) << 2)];
        float cxj = (bj.x + bj.z) * 0.5f, cyj = (bj.y + bj.w) * 0.5f;
        float wdj = bj.z - bj.x + 1.0f,   hgj = bj.w - bj.y + 1.0f;
        float lwj = __logf(wdj), lhj = __logf(hgj);

#pragma unroll
        for (int iu = 0; iu < 2; iu++) {
            const int ii = (ipair << 1) + iu;
            float pos[4];
            pos[0] = __logf(fmaxf(fabsf((cxi[iu] - cxj) / wdi[iu]), 1e-3f));
            pos[1] = __logf(fmaxf(fabsf((cyi[iu] - cyj) / hgi[iu]), 1e-3f));
            pos[2] = lwi[iu] - lwj;
            pos[3] = lhi[iu] - lhj;

#pragma unroll
            for (int p = 0; p < 4; p++) {
                float rev = pos[p] * REV;
                u32x4 sp, cp;
#pragma unroll
                for (int f = 0; f < 4; f++) {
                    float a0 = rev * c_dim_f(2 * f), a1 = rev * c_dim_f(2 * f + 1);
                    sp[f] = (u32)f2b(__builtin_amdgcn_sinf(a0)) | ((u32)f2b(__builtin_amdgcn_sinf(a1)) << 16);
                    cp[f] = (u32)f2b(__builtin_amdgcn_cosf(a0)) | ((u32)f2b(__builtin_amdgcn_cosf(a1)) << 16);
                }
                *(u32x4*)(embs + (((t << 7) + (p << 4)) ^ swz)) = sp;
                *(u32x4*)(embs + (((t << 7) + 64 + (p << 4)) ^ swz)) = cp;
            }
            __syncthreads();

#pragma unroll
            for (int tt = 0; tt < 4; tt++) {
                int mt = (wave << 2) + tt;
                int row = (mt << 4) + hh;
                int rswz = (row & 7) << 4;
                short8 a0v = *(const short8*)(embs + (((row << 7) + (ko << 1)) ^ rswz));
                short8 a1v = *(const short8*)(embs + (((row << 7) + 64 + (ko << 1)) ^ rswz));
                f32x4 acc = {0.f, 0.f, 0.f, 0.f};
                acc = __builtin_amdgcn_mfma_f32_16x16x32_bf16(a0v, bf0, acc, 0, 0, 0);
                acc = __builtin_amdgcn_mfma_f32_16x16x32_bf16(a1v, bf1, acc, 0, 0, 0);
                if (hh < 8) {
                    int j0 = (jt << 8) + (mt << 4) + ((lane >> 4) << 2);
                    u16x4 ow;
#pragma unroll
                    for (int r = 0; r < 4; r++)
                        ow[r] = f2h(fmaxf(acc[r] + bGh, 1e-6f) * 1024.0f);
                    *(u16x4*)&outW[((size_t)((b << 3) + hh) << 18) + ((size_t)ii << 9) + j0] = ow;
                }
            }
            __syncthreads();   // embs reused by next unit
        }
    }
}

// ---------- fused flash attention (R3 structure, f16 bias) ----------
// ONE WAVE per 16 q-rows; serial loop over ALL 8 k-tiles; no cross-wave merge,
// no barriers — tile kt+1's loads overlap tile kt's softmax.
__global__ __launch_bounds__(64) void attn_k(const u16* __restrict__ Qb,
                                             const u16* __restrict__ Kb,
                                             const u16* __restrict__ VT,
                                             const u16* __restrict__ Wp,
                                             u16* __restrict__ ATT) {
    __shared__ u16 Pl[16 * 68];        // P transpose, row stride 68 (2.2KB)
    const int lane = threadIdx.x;
    const int c = lane & 15, g = lane >> 4;
    const int bid = blockIdx.x;
    const int qb = bid & 31, bh = bid >> 5;      // consecutive blocks share (b,h)
    const int b = bh >> 3, h = bh & 7;
    const int q0 = qb << 4;

    const u16* Qp = Qb + ((size_t)bh << 15);     // [512][64]
    const u16* Kp = Kb + ((size_t)bh << 15);     // [512][64]
    const u16* Vp = VT + ((size_t)bh << 15);     // [64][512]
    const _Float16* Bp = (const _Float16*)Wp + ((size_t)bh << 18) + ((size_t)q0 << 9);

    short8 qf[2];
#pragma unroll
    for (int ks = 0; ks < 2; ks++)
        qf[ks] = *(const short8*)&Qp[(size_t)(q0 + c) * 64 + ks * 32 + g * 8];

    f32x4 o[4] = {};
    float m[4] = {-1e30f, -1e30f, -1e30f, -1e30f};
    float l[4] = {0.f, 0.f, 0.f, 0.f};

    for (int kt = 0; kt < 8; kt++) {
        const int k0 = kt << 6;
        short8 kf[4][2], vf[4][2];
#pragma unroll
        for (int jj = 0; jj < 4; jj++)
#pragma unroll
            for (int ks = 0; ks < 2; ks++) {
                kf[jj][ks] = *(const short8*)&Kp[(size_t)(k0 + jj * 16 + c) * 64 + ks * 32 + g * 8];
                vf[jj][ks] = *(const short8*)&Vp[(size_t)(jj * 16 + c) * 512 + k0 + ks * 32 + g * 8];
            }
        float wgt[4][4];
#pragma unroll
        for (int jj = 0; jj < 4; jj++)
#pragma unroll
            for (int r = 0; r < 4; r++)
                wgt[jj][r] = (float)Bp[(size_t)(g * 4 + r) * 512 + k0 + jj * 16 + c];

        f32x4 sa[4] = {};
        __builtin_amdgcn_s_setprio(1);
#pragma unroll
        for (int jj = 0; jj < 4; jj++)
#pragma unroll
            for (int ks = 0; ks < 2; ks++)
                sa[jj] = __builtin_amdgcn_mfma_f32_16x16x32_bf16(qf[ks], kf[jj][ks], sa[jj], 0, 0, 0);
        __builtin_amdgcn_s_setprio(0);

        float s[4][4];
#pragma unroll
        for (int r = 0; r < 4; r++) {
#pragma unroll
            for (int jj = 0; jj < 4; jj++)
                s[jj][r] = sa[jj][r] * 0.125f;
            float v = fmaxf(fmaxf(s[0][r], s[1][r]), fmaxf(s[2][r], s[3][r]));
#pragma unroll
            for (int off = 1; off < 16; off <<= 1)
                v = fmaxf(v, __shfl_xor(v, off));
            float mn = fmaxf(m[r], v);
            float alpha = __expf(m[r] - mn);
            m[r] = mn;
            float rs = 0.f;
#pragma unroll
            for (int jj = 0; jj < 4; jj++) {
                float p = wgt[jj][r] * __expf(s[jj][r] - mn);
                s[jj][r] = p;
                rs += p;
            }
#pragma unroll
            for (int off = 1; off < 16; off <<= 1)
                rs += __shfl_xor(rs, off);
            l[r] = l[r] * alpha + rs;
#pragma unroll
            for (int jjo = 0; jjo < 4; jjo++)
                o[jjo][r] *= alpha;
        }

        // P -> LDS transpose, same-wave ordering via lgkmcnt
#pragma unroll
        for (int jj = 0; jj < 4; jj++)
#pragma unroll
            for (int r = 0; r < 4; r++)
                Pl[(g * 4 + r) * 68 + jj * 16 + c] = f2b(s[jj][r]);
        asm volatile("s_waitcnt lgkmcnt(0)" ::: "memory");
        __builtin_amdgcn_sched_barrier(0);

        short8 pa[2];
#pragma unroll
        for (int ks = 0; ks < 2; ks++)
            pa[ks] = *(const short8*)&Pl[c * 68 + ks * 32 + g * 8];
        __builtin_amdgcn_s_setprio(1);
#pragma unroll
        for (int jjo = 0; jjo < 4; jjo++)
#pragma unroll
            for (int ks = 0; ks < 2; ks++)
                o[jjo] = __builtin_amdgcn_mfma_f32_16x16x32_bf16(pa[ks], vf[jjo][ks], o[jjo], 0, 0, 0);
        __builtin_amdgcn_s_setprio(0);
        __builtin_amdgcn_sched_barrier(0);   // keep next tile's LDS writes behind these reads
    }

#pragma unroll
    for (int r = 0; r < 4; r++) {
        float inv = 1.0f / l[r];
        int row = q0 + g * 4 + r;
#pragma unroll
        for (int jjo = 0; jjo < 4; jjo++)
            ATT[(size_t)(((b << 9) + row) << 9) + (h << 6) + jjo * 16 + c] = f2b(o[jjo][r] * inv);
    }
}

// ---------- merged projection GEMM (dbuf counted-vmcnt staging) ----------
__global__ __launch_bounds__(256) void proj_k(const u16* __restrict__ Xall,
                                              const u16* __restrict__ Wall,
                                              const float* __restrict__ bq,
                                              const float* __restrict__ bk,
                                              const float* __restrict__ bv,
                                              u16* __restrict__ Qb,
                                              u16* __restrict__ Kb,
                                              u16* __restrict__ VT) {
    __shared__ u16 As[2][64 * 32];
    __shared__ u16 Bs[2][64 * 32];

    const int t = threadIdx.x;
    const int wave = t >> 6, lane = t & 63;
    const int wr = wave >> 1, wc = wave & 1;
    const int m0 = blockIdx.y * 64, n0 = blockIdx.x * 64;
    const int z = blockIdx.z;

    const u16* A  = Xall + (size_t)z * 1048576;
    const u16* Bm = Wall + (size_t)z * 262144;
    const float* bias = (z == 0) ? bq : (z == 1) ? bk : bv;
    u16* out = (z == 0) ? Qb : (z == 1) ? Kb : VT;

    f32x4 acc[2][2] = {};
    const int srow = t >> 2;
    const int scol = (((t & 3) ^ ((t >> 3) & 3)) << 3);
    const int c = lane & 15, g = lane >> 4;
    const int gsw = (g ^ ((c >> 1) & 3)) << 3;

    const size_t arow = (size_t)(m0 + srow) * 512 + scol;
    const size_t brow = (size_t)(n0 + srow) * 512 + scol;

    gload_lds16(&A[arow], &As[0][t * 8]);
    gload_lds16(&Bm[brow], &Bs[0][t * 8]);

    int cur = 0;
    for (int k0 = 0; k0 < 512; k0 += 32, cur ^= 1) {
        if (k0 + 32 < 512) {
            gload_lds16(&A[arow + k0 + 32], &As[cur ^ 1][t * 8]);
            gload_lds16(&Bm[brow + k0 + 32], &Bs[cur ^ 1][t * 8]);
            asm volatile("s_waitcnt vmcnt(2)" ::: "memory");
        } else {
            asm volatile("s_waitcnt vmcnt(0)" ::: "memory");
        }
        __builtin_amdgcn_s_barrier();
        __builtin_amdgcn_sched_barrier(0);
        short8 af[2], bfr[2];
#pragma unroll
        for (int i = 0; i < 2; i++)
            af[i] = *(const short8*)&As[cur][(wr * 32 + i * 16 + c) * 32 + gsw];
#pragma unroll
        for (int jj = 0; jj < 2; jj++)
            bfr[jj] = *(const short8*)&Bs[cur][(wc * 32 + jj * 16 + c) * 32 + gsw];
#pragma unroll
        for (int i = 0; i < 2; i++)
#pragma unroll
            for (int jj = 0; jj < 2; jj++)
                acc[i][jj] = __builtin_amdgcn_mfma_f32_16x16x32_bf16(af[i], bfr[jj], acc[i][jj], 0, 0, 0);
        __builtin_amdgcn_sched_barrier(0);
        __builtin_amdgcn_s_barrier();
    }

#pragma unroll
    for (int i = 0; i < 2; i++)
#pragma unroll
        for (int jj = 0; jj < 2; jj++)
#pragma unroll
            for (int r = 0; r < 4; r++) {
                int row = m0 + wr * 32 + i * 16 + ((lane >> 4) << 2) + r;
                int col = n0 + wc * 32 + jj * 16 + (lane & 15);
                float v = acc[i][jj][r] + bias[col];
                int b = row >> 9, rr = row & 511, h = col >> 6, d = col & 63;
                if (z < 2)
                    out[(size_t)((((b << 3) + h) << 9) + rr) * 64 + d] = f2b(v);
                else
                    out[(size_t)((((b << 3) + h) << 6) + d) * 512 + rr] = f2b(v);
            }
}

// ---------- output GEMM (dbuf staging) ----------
__global__ __launch_bounds__(256) void outg_k(const u16* __restrict__ A,
                                              const u16* __restrict__ Bm,
                                              const float* __restrict__ bias,
                                              float* __restrict__ outF) {
    __shared__ u16 As[2][64 * 32];
    __shared__ u16 Bs[2][64 * 32];

    const int t = threadIdx.x;
    const int wave = t >> 6, lane = t & 63;
    const int wr = wave >> 1, wc = wave & 1;
    const int m0 = blockIdx.y * 64, n0 = blockIdx.x * 64;

    f32x4 acc[2][2] = {};
    const int srow = t >> 2;
    const int scol = (((t & 3) ^ ((t >> 3) & 3)) << 3);
    const int c = lane & 15, g = lane >> 4;
    const int gsw = (g ^ ((c >> 1) & 3)) << 3;

    const size_t arow = (size_t)(m0 + srow) * 512 + scol;
    const size_t brow = (size_t)(n0 + srow) * 512 + scol;

    gload_lds16(&A[arow], &As[0][t * 8]);
    gload_lds16(&Bm[brow], &Bs[0][t * 8]);

    int cur = 0;
    for (int k0 = 0; k0 < 512; k0 += 32, cur ^= 1) {
        if (k0 + 32 < 512) {
            gload_lds16(&A[arow + k0 + 32], &As[cur ^ 1][t * 8]);
            gload_lds16(&Bm[brow + k0 + 32], &Bs[cur ^ 1][t * 8]);
            asm volatile("s_waitcnt vmcnt(2)" ::: "memory");
        } else {
            asm volatile("s_waitcnt vmcnt(0)" ::: "memory");
        }
        __builtin_amdgcn_s_barrier();
        __builtin_amdgcn_sched_barrier(0);
        short8 af[2], bfr[2];
#pragma unroll
        for (int i = 0; i < 2; i++)
            af[i] = *(const short8*)&As[cur][(wr * 32 + i * 16 + c) * 32 + gsw];
#pragma unroll
        for (int jj = 0; jj < 2; jj++)
            bfr[jj] = *(const short8*)&Bs[cur][(wc * 32 + jj * 16 + c) * 32 + gsw];
#pragma unroll
        for (int i = 0; i < 2; i++)
#pragma unroll
            for (int jj = 0; jj < 2; jj++)
                acc[i][jj] = __builtin_amdgcn_mfma_f32_16x16x32_bf16(af[i], bfr[jj], acc[i][jj], 0, 0, 0);
        __builtin_amdgcn_sched_barrier(0);
        __builtin_amdgcn_s_barrier();
    }

#pragma unroll
    for (int i = 0; i < 2; i++)
#pragma unroll
        for (int jj = 0; jj < 2; jj++)
#pragma unroll
            for (int r = 0; r < 4; r++) {
                int row = m0 + wr * 32 + i * 16 + ((lane >> 4) << 2) + r;
                int col = n0 + wc * 32 + jj * 16 + (lane & 15);
                outF[((size_t)row << 9) + col] = acc[i][jj][r] + bias[col];
            }
}

// ---------- launch ----------
extern "C" void kernel_launch(void* const* d_in, const int* in_sizes, int n_in,
                              void* d_out, int out_size, void* d_ws, size_t ws_size,
                              hipStream_t stream) {
    const float* inq = (const float*)d_in[0];
    const float* ink = (const float*)d_in[1];
    const float* inv = (const float*)d_in[2];
    const float* box = (const float*)d_in[3];
    const float* Wq  = (const float*)d_in[4];
    const float* bq  = (const float*)d_in[5];
    const float* Wk  = (const float*)d_in[6];
    const float* bk  = (const float*)d_in[7];
    const float* Wv  = (const float*)d_in[8];
    const float* bv  = (const float*)d_in[9];
    const float* Wo  = (const float*)d_in[10];
    const float* bo  = (const float*)d_in[11];
    const float* WG  = (const float*)d_in[12];
    const float* bG  = (const float*)d_in[13];

    u16* base = (u16*)d_ws;
    u16* Xall = base;                    // XQ,XK,XV bf16 (3 x 1,048,576)
    u16* Wall = base + 3145728;          // WQb,WKb,WVb,WOb bf16 (4 x 262,144)
    u16* Qb   = base + 4194304;          // [B,H,N,64] bf16
    u16* Kb   = base + 5242880;          // [B,H,N,64] bf16
    u16* VT   = base + 6291456;          // [B,H,64,N] bf16
    u16* ATT  = base + 7340032;          // [B,N,512] bf16
    u16* Wp   = base + 8388608;          // [B,H,N,N] f16 geometry weights

    prep_k<<<dim3(1024, 1, 11), 256, 0, stream>>>(inq, ink, inv, Wq, Wk, Wv, Wo,
                                                  box, WG, bG, Xall, Wall, Wp);

    proj_k<<<dim3(8, 32, 3), 256, 0, stream>>>(Xall, Wall, bq, bk, bv, Qb, Kb, VT);

    attn_k<<<dim3(1024), 64, 0, stream>>>(Qb, Kb, VT, Wp, ATT);

    outg_k<<<dim3(8, 32, 1), 256, 0, stream>>>(ATT, Wall + 786432, bo, (float*)d_out);
}

// Round 18
// 67.744 us; speedup vs baseline: 6.6186x; 1.0178x over previous
//
#include <hip/hip_runtime.h>
#include <hip/hip_bf16.h>
#include <cstdint>

typedef unsigned short u16;
typedef unsigned int u32;
typedef __attribute__((ext_vector_type(8))) short short8;   // 8 bf16 MFMA A/B frag
typedef __attribute__((ext_vector_type(4))) float f32x4;    // MFMA C/D frag
typedef __attribute__((ext_vector_type(4))) unsigned int u32x4;
typedef __attribute__((ext_vector_type(4))) unsigned short u16x4;

#define REV 15.91549431f   // 100/(2*pi): the "100*pos" angle in revolutions

// ---------- helpers ----------
__device__ __forceinline__ u16 f2b(float x) { return __builtin_bit_cast(u16, (__bf16)x); }
__device__ __forceinline__ u16 f2h(float x) { return __builtin_bit_cast(u16, (_Float16)x); }
__device__ __forceinline__ float c_dim_f(int f) {
    const float c[8] = {1.0f, 0.42169650f, 0.17782794f, 0.074989421f,
                        0.031622777f, 0.013335214f, 0.0056234132f, 0.0023713737f};
    return c[f];
}
__device__ __forceinline__ void gload_lds16(const void* g, void* l) {
    __builtin_amdgcn_global_load_lds((const __attribute__((address_space(1))) u32*)g,
                                     (__attribute__((address_space(3))) u32*)l, 16, 0, 0);
}

// ---------- prep: f32->bf16 cvt (z 0..6, needs 1024 x-blocks) ----------
// ----------       geometry weights (z 7..10, first 256 x-blocks) --------
__global__ __launch_bounds__(256) void prep_k(const float* __restrict__ s0,
                                              const float* __restrict__ s1,
                                              const float* __restrict__ s2,
                                              const float* __restrict__ s3,
                                              const float* __restrict__ s4,
                                              const float* __restrict__ s5,
                                              const float* __restrict__ s6,
                                              const float* __restrict__ box,
                                              const float* __restrict__ WG,
                                              const float* __restrict__ bG,
                                              u16* __restrict__ dstX,
                                              u16* __restrict__ dstW,
                                              u16* __restrict__ outW) {
    __shared__ char embs[256 * 128];   // [256 pairs][64 bf16] rows, 128B each
    const int z = blockIdx.z;
    const int t = threadIdx.x;

    if (z < 7) {
        const float* s;
        u16* dst;
        if (z < 3) {
            s = (z == 0) ? s0 : (z == 1) ? s1 : s2;
            dst = dstX + (size_t)z * 1048576;
        } else {
            if (blockIdx.x >= 256) return;
            s = (z == 3) ? s3 : (z == 4) ? s4 : (z == 5) ? s5 : s6;
            dst = dstW + (size_t)(z - 3) * 262144;
        }
        int i = (blockIdx.x * 256 + t) * 4;
        float4 v = *(const float4*)&s[i];
        u16x4 o = { f2b(v.x), f2b(v.y), f2b(v.z), f2b(v.w) };
        *(u16x4*)&dst[i] = o;
        return;
    }

    // ---------------- geometry: 4 units per block ----------------
    if (blockIdx.x >= 256) return;
    const int wave = t >> 6, lane = t & 63;
    const int b = z - 7;
    const int ipair = blockIdx.x;          // i = 2*ipair, 2*ipair+1
    const int swz = (t & 7) << 4;

    float cxi[2], cyi[2], wdi[2], hgi[2], lwi[2], lhi[2];
#pragma unroll
    for (int iu = 0; iu < 2; iu++) {
        int ii = (ipair << 1) + iu;
        float4 bi = *(const float4*)&box[(size_t)(((b << 9) + ii) << 2)];
        cxi[iu] = (bi.x + bi.z) * 0.5f; cyi[iu] = (bi.y + bi.w) * 0.5f;
        wdi[iu] = bi.z - bi.x + 1.0f;   hgi[iu] = bi.w - bi.y + 1.0f;
        lwi[iu] = __logf(wdi[iu]);      lhi[iu] = __logf(hgi[iu]);
    }

    const int hh = lane & 15;
    const int ko = (lane >> 4) << 3;
    short8 bf0 = {0,0,0,0,0,0,0,0}, bf1 = {0,0,0,0,0,0,0,0};
    float bGh = 0.0f;
    if (hh < 8) {
        const float* wrow = WG + hh * 64;
#pragma unroll
        for (int e = 0; e < 8; e++) {
            bf0[e] = (short)f2b(wrow[ko + e]);
            bf1[e] = (short)f2b(wrow[32 + ko + e]);
        }
        bGh = bG[hh];
    }

    for (int jt = 0; jt < 2; jt++) {
        const int j = (jt << 8) + t;
        float4 bj = *(const float4*)&box[(size_t)(((b << 9) + j) << 2)];
        float cxj = (bj.x + bj.z) * 0.5f, cyj = (bj.y + bj.w) * 0.5f;
        float wdj = bj.z - bj.x + 1.0f,   hgj = bj.w - bj.y + 1.0f;
        float lwj = __logf(wdj), lhj = __logf(hgj);

#pragma unroll
        for (int iu = 0; iu < 2; iu++) {
            const int ii = (ipair << 1) + iu;
            float pos[4];
            pos[0] = __logf(fmaxf(fabsf((cxi[iu] - cxj) / wdi[iu]), 1e-3f));
            pos[1] = __logf(fmaxf(fabsf((cyi[iu] - cyj) / hgi[iu]), 1e-3f));
            pos[2] = lwi[iu] - lwj;
            pos[3] = lhi[iu] - lhj;

#pragma unroll
            for (int p = 0; p < 4; p++) {
                float rev = pos[p] * REV;
                u32x4 sp, cp;
#pragma unroll
                for (int f = 0; f < 4; f++) {
                    float a0 = rev * c_dim_f(2 * f), a1 = rev * c_dim_f(2 * f + 1);
                    sp[f] = (u32)f2b(__builtin_amdgcn_sinf(a0)) | ((u32)f2b(__builtin_amdgcn_sinf(a1)) << 16);
                    cp[f] = (u32)f2b(__builtin_amdgcn_cosf(a0)) | ((u32)f2b(__builtin_amdgcn_cosf(a1)) << 16);
                }
                *(u32x4*)(embs + (((t << 7) + (p << 4)) ^ swz)) = sp;
                *(u32x4*)(embs + (((t << 7) + 64 + (p << 4)) ^ swz)) = cp;
            }
            __syncthreads();

#pragma unroll
            for (int tt = 0; tt < 4; tt++) {
                int mt = (wave << 2) + tt;
                int row = (mt << 4) + hh;
                int rswz = (row & 7) << 4;
                short8 a0v = *(const short8*)(embs + (((row << 7) + (ko << 1)) ^ rswz));
                short8 a1v = *(const short8*)(embs + (((row << 7) + 64 + (ko << 1)) ^ rswz));
                f32x4 acc = {0.f, 0.f, 0.f, 0.f};
                acc = __builtin_amdgcn_mfma_f32_16x16x32_bf16(a0v, bf0, acc, 0, 0, 0);
                acc = __builtin_amdgcn_mfma_f32_16x16x32_bf16(a1v, bf1, acc, 0, 0, 0);
                if (hh < 8) {
                    int j0 = (jt << 8) + (mt << 4) + ((lane >> 4) << 2);
                    u16x4 ow;
#pragma unroll
                    for (int r = 0; r < 4; r++)
                        ow[r] = f2h(fmaxf(acc[r] + bGh, 1e-6f) * 1024.0f);
                    *(u16x4*)&outW[((size_t)((b << 3) + hh) << 18) + ((size_t)ii << 9) + j0] = ow;
                }
            }
            __syncthreads();   // embs reused by next unit
        }
    }
}

// ---------- fused flash attention (1-wave serial-k, ILP softmax) ----------
// ONE WAVE per 16 q-rows; serial over 8 k-tiles; no barriers. Softmax
// reductions ILP-interleaved across the 4 r-rows: 4 independent shfl/exp
// chains overlap (same trees per row -> bit-identical results).
__global__ __launch_bounds__(64) void attn_k(const u16* __restrict__ Qb,
                                             const u16* __restrict__ Kb,
                                             const u16* __restrict__ VT,
                                             const u16* __restrict__ Wp,
                                             u16* __restrict__ ATT) {
    __shared__ u16 Pl[16 * 68];        // P transpose, row stride 68 (2.2KB)
    const int lane = threadIdx.x;
    const int c = lane & 15, g = lane >> 4;
    const int bid = blockIdx.x;
    const int qb = bid & 31, bh = bid >> 5;      // consecutive blocks share (b,h)
    const int b = bh >> 3, h = bh & 7;
    const int q0 = qb << 4;

    const u16* Qp = Qb + ((size_t)bh << 15);     // [512][64]
    const u16* Kp = Kb + ((size_t)bh << 15);     // [512][64]
    const u16* Vp = VT + ((size_t)bh << 15);     // [64][512]
    const _Float16* Bp = (const _Float16*)Wp + ((size_t)bh << 18) + ((size_t)q0 << 9);

    short8 qf[2];
#pragma unroll
    for (int ks = 0; ks < 2; ks++)
        qf[ks] = *(const short8*)&Qp[(size_t)(q0 + c) * 64 + ks * 32 + g * 8];

    f32x4 o[4] = {};
    float m[4] = {-1e30f, -1e30f, -1e30f, -1e30f};
    float l[4] = {0.f, 0.f, 0.f, 0.f};

    for (int kt = 0; kt < 8; kt++) {
        const int k0 = kt << 6;
        short8 kf[4][2], vf[4][2];
#pragma unroll
        for (int jj = 0; jj < 4; jj++)
#pragma unroll
            for (int ks = 0; ks < 2; ks++) {
                kf[jj][ks] = *(const short8*)&Kp[(size_t)(k0 + jj * 16 + c) * 64 + ks * 32 + g * 8];
                vf[jj][ks] = *(const short8*)&Vp[(size_t)(jj * 16 + c) * 512 + k0 + ks * 32 + g * 8];
            }
        float wgt[4][4];
#pragma unroll
        for (int jj = 0; jj < 4; jj++)
#pragma unroll
            for (int r = 0; r < 4; r++)
                wgt[jj][r] = (float)Bp[(size_t)(g * 4 + r) * 512 + k0 + jj * 16 + c];

        f32x4 sa[4] = {};
        __builtin_amdgcn_s_setprio(1);
#pragma unroll
        for (int jj = 0; jj < 4; jj++)
#pragma unroll
            for (int ks = 0; ks < 2; ks++)
                sa[jj] = __builtin_amdgcn_mfma_f32_16x16x32_bf16(qf[ks], kf[jj][ks], sa[jj], 0, 0, 0);
        __builtin_amdgcn_s_setprio(0);

        float s[4][4];
#pragma unroll
        for (int r = 0; r < 4; r++)
#pragma unroll
            for (int jj = 0; jj < 4; jj++)
                s[jj][r] = sa[jj][r] * 0.125f;

        // ---- row-max: 4 independent shfl chains (ILP) ----
        float vmax[4];
#pragma unroll
        for (int r = 0; r < 4; r++)
            vmax[r] = fmaxf(fmaxf(s[0][r], s[1][r]), fmaxf(s[2][r], s[3][r]));
#pragma unroll
        for (int off = 1; off < 16; off <<= 1)
#pragma unroll
            for (int r = 0; r < 4; r++)
                vmax[r] = fmaxf(vmax[r], __shfl_xor(vmax[r], off));

        float alpha[4];
#pragma unroll
        for (int r = 0; r < 4; r++) {
            float mn = fmaxf(m[r], vmax[r]);
            alpha[r] = __expf(m[r] - mn);
            m[r] = mn;
        }

        // ---- p = w * exp(s - m): 16 independent exps, then 4 sum chains ----
        float rs[4] = {0.f, 0.f, 0.f, 0.f};
#pragma unroll
        for (int r = 0; r < 4; r++)
#pragma unroll
            for (int jj = 0; jj < 4; jj++) {
                float p = wgt[jj][r] * __expf(s[jj][r] - m[r]);
                s[jj][r] = p;
                rs[r] += p;
            }
#pragma unroll
        for (int off = 1; off < 16; off <<= 1)
#pragma unroll
            for (int r = 0; r < 4; r++)
                rs[r] += __shfl_xor(rs[r], off);
#pragma unroll
        for (int r = 0; r < 4; r++)
            l[r] = l[r] * alpha[r] + rs[r];
#pragma unroll
        for (int jjo = 0; jjo < 4; jjo++)
#pragma unroll
            for (int r = 0; r < 4; r++)
                o[jjo][r] *= alpha[r];

        // P -> LDS transpose, same-wave ordering via lgkmcnt
#pragma unroll
        for (int jj = 0; jj < 4; jj++)
#pragma unroll
            for (int r = 0; r < 4; r++)
                Pl[(g * 4 + r) * 68 + jj * 16 + c] = f2b(s[jj][r]);
        asm volatile("s_waitcnt lgkmcnt(0)" ::: "memory");
        __builtin_amdgcn_sched_barrier(0);

        short8 pa[2];
#pragma unroll
        for (int ks = 0; ks < 2; ks++)
            pa[ks] = *(const short8*)&Pl[c * 68 + ks * 32 + g * 8];
        __builtin_amdgcn_s_setprio(1);
#pragma unroll
        for (int jjo = 0; jjo < 4; jjo++)
#pragma unroll
            for (int ks = 0; ks < 2; ks++)
                o[jjo] = __builtin_amdgcn_mfma_f32_16x16x32_bf16(pa[ks], vf[jjo][ks], o[jjo], 0, 0, 0);
        __builtin_amdgcn_s_setprio(0);
        __builtin_amdgcn_sched_barrier(0);   // keep next tile's LDS writes behind these reads
    }

#pragma unroll
    for (int r = 0; r < 4; r++) {
        float inv = 1.0f / l[r];
        int row = q0 + g * 4 + r;
#pragma unroll
        for (int jjo = 0; jjo < 4; jjo++)
            ATT[(size_t)(((b << 9) + row) << 9) + (h << 6) + jjo * 16 + c] = f2b(o[jjo][r] * inv);
    }
}

// ---------- merged projection GEMM (dbuf counted-vmcnt staging) ----------
__global__ __launch_bounds__(256) void proj_k(const u16* __restrict__ Xall,
                                              const u16* __restrict__ Wall,
                                              const float* __restrict__ bq,
                                              const float* __restrict__ bk,
                                              const float* __restrict__ bv,
                                              u16* __restrict__ Qb,
                                              u16* __restrict__ Kb,
                                              u16* __restrict__ VT) {
    __shared__ u16 As[2][64 * 32];
    __shared__ u16 Bs[2][64 * 32];

    const int t = threadIdx.x;
    const int wave = t >> 6, lane = t & 63;
    const int wr = wave >> 1, wc = wave & 1;
    const int m0 = blockIdx.y * 64, n0 = blockIdx.x * 64;
    const int z = blockIdx.z;

    const u16* A  = Xall + (size_t)z * 1048576;
    const u16* Bm = Wall + (size_t)z * 262144;
    const float* bias = (z == 0) ? bq : (z == 1) ? bk : bv;
    u16* out = (z == 0) ? Qb : (z == 1) ? Kb : VT;

    f32x4 acc[2][2] = {};
    const int srow = t >> 2;
    const int scol = (((t & 3) ^ ((t >> 3) & 3)) << 3);
    const int c = lane & 15, g = lane >> 4;
    const int gsw = (g ^ ((c >> 1) & 3)) << 3;

    const size_t arow = (size_t)(m0 + srow) * 512 + scol;
    const size_t brow = (size_t)(n0 + srow) * 512 + scol;

    gload_lds16(&A[arow], &As[0][t * 8]);
    gload_lds16(&Bm[brow], &Bs[0][t * 8]);

    int cur = 0;
    for (int k0 = 0; k0 < 512; k0 += 32, cur ^= 1) {
        if (k0 + 32 < 512) {
            gload_lds16(&A[arow + k0 + 32], &As[cur ^ 1][t * 8]);
            gload_lds16(&Bm[brow + k0 + 32], &Bs[cur ^ 1][t * 8]);
            asm volatile("s_waitcnt vmcnt(2)" ::: "memory");
        } else {
            asm volatile("s_waitcnt vmcnt(0)" ::: "memory");
        }
        __builtin_amdgcn_s_barrier();
        __builtin_amdgcn_sched_barrier(0);
        short8 af[2], bfr[2];
#pragma unroll
        for (int i = 0; i < 2; i++)
            af[i] = *(const short8*)&As[cur][(wr * 32 + i * 16 + c) * 32 + gsw];
#pragma unroll
        for (int jj = 0; jj < 2; jj++)
            bfr[jj] = *(const short8*)&Bs[cur][(wc * 32 + jj * 16 + c) * 32 + gsw];
#pragma unroll
        for (int i = 0; i < 2; i++)
#pragma unroll
            for (int jj = 0; jj < 2; jj++)
                acc[i][jj] = __builtin_amdgcn_mfma_f32_16x16x32_bf16(af[i], bfr[jj], acc[i][jj], 0, 0, 0);
        __builtin_amdgcn_sched_barrier(0);
        __builtin_amdgcn_s_barrier();
    }

#pragma unroll
    for (int i = 0; i < 2; i++)
#pragma unroll
        for (int jj = 0; jj < 2; jj++)
#pragma unroll
            for (int r = 0; r < 4; r++) {
                int row = m0 + wr * 32 + i * 16 + ((lane >> 4) << 2) + r;
                int col = n0 + wc * 32 + jj * 16 + (lane & 15);
                float v = acc[i][jj][r] + bias[col];
                int b = row >> 9, rr = row & 511, h = col >> 6, d = col & 63;
                if (z < 2)
                    out[(size_t)((((b << 3) + h) << 9) + rr) * 64 + d] = f2b(v);
                else
                    out[(size_t)((((b << 3) + h) << 6) + d) * 512 + rr] = f2b(v);
            }
}

// ---------- output GEMM (dbuf staging) ----------
__global__ __launch_bounds__(256) void outg_k(const u16* __restrict__ A,
                                              const u16* __restrict__ Bm,
                                              const float* __restrict__ bias,
                                              float* __restrict__ outF) {
    __shared__ u16 As[2][64 * 32];
    __shared__ u16 Bs[2][64 * 32];

    const int t = threadIdx.x;
    const int wave = t >> 6, lane = t & 63;
    const int wr = wave >> 1, wc = wave & 1;
    const int m0 = blockIdx.y * 64, n0 = blockIdx.x * 64;

    f32x4 acc[2][2] = {};
    const int srow = t >> 2;
    const int scol = (((t & 3) ^ ((t >> 3) & 3)) << 3);
    const int c = lane & 15, g = lane >> 4;
    const int gsw = (g ^ ((c >> 1) & 3)) << 3;

    const size_t arow = (size_t)(m0 + srow) * 512 + scol;
    const size_t brow = (size_t)(n0 + srow) * 512 + scol;

    gload_lds16(&A[arow], &As[0][t * 8]);
    gload_lds16(&Bm[brow], &Bs[0][t * 8]);

    int cur = 0;
    for (int k0 = 0; k0 < 512; k0 += 32, cur ^= 1) {
        if (k0 + 32 < 512) {
            gload_lds16(&A[arow + k0 + 32], &As[cur ^ 1][t * 8]);
            gload_lds16(&Bm[brow + k0 + 32], &Bs[cur ^ 1][t * 8]);
            asm volatile("s_waitcnt vmcnt(2)" ::: "memory");
        } else {
            asm volatile("s_waitcnt vmcnt(0)" ::: "memory");
        }
        __builtin_amdgcn_s_barrier();
        __builtin_amdgcn_sched_barrier(0);
        short8 af[2], bfr[2];
#pragma unroll
        for (int i = 0; i < 2; i++)
            af[i] = *(const short8*)&As[cur][(wr * 32 + i * 16 + c) * 32 + gsw];
#pragma unroll
        for (int jj = 0; jj < 2; jj++)
            bfr[jj] = *(const short8*)&Bs[cur][(wc * 32 + jj * 16 + c) * 32 + gsw];
#pragma unroll
        for (int i = 0; i < 2; i++)
#pragma unroll
            for (int jj = 0; jj < 2; jj++)
                acc[i][jj] = __builtin_amdgcn_mfma_f32_16x16x32_bf16(af[i], bfr[jj], acc[i][jj], 0, 0, 0);
        __builtin_amdgcn_sched_barrier(0);
        __builtin_amdgcn_s_barrier();
    }

#pragma unroll
    for (int i = 0; i < 2; i++)
#pragma unroll
        for (int jj = 0; jj < 2; jj++)
#pragma unroll
            for (int r = 0; r < 4; r++) {
                int row = m0 + wr * 32 + i * 16 + ((lane >> 4) << 2) + r;
                int col = n0 + wc * 32 + jj * 16 + (lane & 15);
                outF[((size_t)row << 9) + col] = acc[i][jj][r] + bias[col];
            }
}

// ---------- launch ----------
extern "C" void kernel_launch(void* const* d_in, const int* in_sizes, int n_in,
                              void* d_out, int out_size, void* d_ws, size_t ws_size,
                              hipStream_t stream) {
    const float* inq = (const float*)d_in[0];
    const float* ink = (const float*)d_in[1];
    const float* inv = (const float*)d_in[2];
    const float* box = (const float*)d_in[3];
    const float* Wq  = (const float*)d_in[4];
    const float* bq  = (const float*)d_in[5];
    const float* Wk  = (const float*)d_in[6];
    const float* bk  = (const float*)d_in[7];
    const float* Wv  = (const float*)d_in[8];
    const float* bv  = (const float*)d_in[9];
    const float* Wo  = (const float*)d_in[10];
    const float* bo  = (const float*)d_in[11];
    const float* WG  = (const float*)d_in[12];
    const float* bG  = (const float*)d_in[13];

    u16* base = (u16*)d_ws;
    u16* Xall = base;                    // XQ,XK,XV bf16 (3 x 1,048,576)
    u16* Wall = base + 3145728;          // WQb,WKb,WVb,WOb bf16 (4 x 262,144)
    u16* Qb   = base + 4194304;          // [B,H,N,64] bf16
    u16* Kb   = base + 5242880;          // [B,H,N,64] bf16
    u16* VT   = base + 6291456;          // [B,H,64,N] bf16
    u16* ATT  = base + 7340032;          // [B,N,512] bf16
    u16* Wp   = base + 8388608;          // [B,H,N,N] f16 geometry weights

    prep_k<<<dim3(1024, 1, 11), 256, 0, stream>>>(inq, ink, inv, Wq, Wk, Wv, Wo,
                                                  box, WG, bG, Xall, Wall, Wp);

    proj_k<<<dim3(8, 32, 3), 256, 0, stream>>>(Xall, Wall, bq, bk, bv, Qb, Kb, VT);

    attn_k<<<dim3(1024), 64, 0, stream>>>(Qb, Kb, VT, Wp, ATT);

    outg_k<<<dim3(8, 32, 1), 256, 0, stream>>>(ATT, Wall + 786432, bo, (float*)d_out);
}